// Round 1
// baseline (1779.302 us; speedup 1.0000x reference)
//
#include <hip/hip_runtime.h>
#include <hip/hip_bf16.h>
#include <math.h>
#include <float.h>

#define T_ROWS 131072   // 32 * 4096 patches
#define DKD 256
#define NVOCAB 512

__device__ __forceinline__ float gelu_f(float x){
    return 0.5f * x * (1.0f + erff(x * 0.7071067811865475f));
}

// ---------------------------------------------------------------------------
// Generic tiled GEMM: C[M,256] = act(A[M,K] @ W[256,K]^T + b)
// BM=128, BN=128, BK=16, 256 threads, 8x8 microtile.
// LOADER: 0 = plain A (row-major [M,K])
//         1 = patchify+normalize from frames (K must be 48)
//         2 = gather codebook rows via float tokens
// ---------------------------------------------------------------------------
template<int K, bool GELU, int LOADER>
__global__ __launch_bounds__(256) void gemm_kernel(
    const float* __restrict__ Ain,
    const float* __restrict__ frames,
    const float* __restrict__ codebook,
    const float* __restrict__ tokf,
    const float* __restrict__ W,
    const float* __restrict__ bias,
    float* __restrict__ Cout)
{
    constexpr int BM=128, BN=128, BK=16;
    __shared__ __align__(16) float As[BK][BM+4];
    __shared__ __align__(16) float Ws[BK][BN+4];

    const int tid = threadIdx.x;
    const int tx = tid & 15, ty = tid >> 4;
    const int m0 = blockIdx.x * BM;
    const int c0 = blockIdx.y * BN;

    const int q  = tid & 3;      // k-quad within BK
    const int r0 = tid >> 2;     // 0..63 ; rows r0 and r0+64

    const float* aptr0 = nullptr;
    const float* aptr1 = nullptr;
    int base0 = 0, base1 = 0;
    if constexpr (LOADER == 0){
        aptr0 = Ain + (size_t)(m0 + r0) * K;
        aptr1 = aptr0 + (size_t)64 * K;
    } else if constexpr (LOADER == 1){
        int p0 = m0 + r0;
        int b = p0 >> 12, nl = p0 & 4095, hh = nl >> 6, ww = nl & 63;
        base0 = ((b*256 + hh*4)*256 + ww*4)*3;
        int p1 = p0 + 64;
        b = p1 >> 12; nl = p1 & 4095; hh = nl >> 6; ww = nl & 63;
        base1 = ((b*256 + hh*4)*256 + ww*4)*3;
    } else {
        int g0 = (int)tokf[m0 + r0];
        int g1 = (int)tokf[m0 + r0 + 64];
        aptr0 = codebook + (size_t)g0 * 256;
        aptr1 = codebook + (size_t)g1 * 256;
    }
    const float* wptr0 = W + (size_t)(c0 + r0) * K;
    const float* wptr1 = wptr0 + (size_t)64 * K;

    float acc[8][8];
    #pragma unroll
    for (int i=0;i<8;++i)
        #pragma unroll
        for (int j=0;j<8;++j) acc[i][j] = 0.0f;

    for (int k0 = 0; k0 < K; k0 += BK){
        const int k = k0 + q*4;
        float4 va, vb;
        if constexpr (LOADER == 1){
            const int ph = k / 12, rem = k - ph*12;
            va = *(const float4*)(frames + base0 + ph*768 + rem);
            vb = *(const float4*)(frames + base1 + ph*768 + rem);
            const float sc = 2.0f/255.0f;
            va.x = va.x*sc - 1.0f; va.y = va.y*sc - 1.0f;
            va.z = va.z*sc - 1.0f; va.w = va.w*sc - 1.0f;
            vb.x = vb.x*sc - 1.0f; vb.y = vb.y*sc - 1.0f;
            vb.z = vb.z*sc - 1.0f; vb.w = vb.w*sc - 1.0f;
        } else {
            va = *(const float4*)(aptr0 + k);
            vb = *(const float4*)(aptr1 + k);
        }
        As[q*4+0][r0]    = va.x; As[q*4+1][r0]    = va.y;
        As[q*4+2][r0]    = va.z; As[q*4+3][r0]    = va.w;
        As[q*4+0][r0+64] = vb.x; As[q*4+1][r0+64] = vb.y;
        As[q*4+2][r0+64] = vb.z; As[q*4+3][r0+64] = vb.w;

        float4 wa = *(const float4*)(wptr0 + k);
        float4 wb = *(const float4*)(wptr1 + k);
        Ws[q*4+0][r0]    = wa.x; Ws[q*4+1][r0]    = wa.y;
        Ws[q*4+2][r0]    = wa.z; Ws[q*4+3][r0]    = wa.w;
        Ws[q*4+0][r0+64] = wb.x; Ws[q*4+1][r0+64] = wb.y;
        Ws[q*4+2][r0+64] = wb.z; Ws[q*4+3][r0+64] = wb.w;

        __syncthreads();
        #pragma unroll
        for (int kk=0; kk<BK; ++kk){
            float a[8], b[8];
            *(float4*)&a[0] = *(const float4*)&As[kk][ty*8];
            *(float4*)&a[4] = *(const float4*)&As[kk][ty*8+4];
            *(float4*)&b[0] = *(const float4*)&Ws[kk][tx*8];
            *(float4*)&b[4] = *(const float4*)&Ws[kk][tx*8+4];
            #pragma unroll
            for (int i=0;i<8;++i)
                #pragma unroll
                for (int j=0;j<8;++j)
                    acc[i][j] = fmaf(a[i], b[j], acc[i][j]);
        }
        __syncthreads();
    }

    float bj[8];
    #pragma unroll
    for (int j=0;j<8;++j) bj[j] = bias[c0 + tx*8 + j];
    #pragma unroll
    for (int i=0;i<8;++i){
        const int row = m0 + ty*8 + i;
        float o[8];
        #pragma unroll
        for (int j=0;j<8;++j){
            float x = acc[i][j] + bj[j];
            o[j] = GELU ? gelu_f(x) : x;
        }
        float* dst = Cout + (size_t)row*256 + c0 + tx*8;
        *(float4*)dst     = *(const float4*)&o[0];
        *(float4*)(dst+4) = *(const float4*)&o[4];
    }
}

// ---------------------------------------------------------------------------
// Token assignment: for 128 patches/block, scan 512 codes in 4 chunks of 128.
// d2 = (||z||^2 - 2*z.c) + ||c||^2   (matches reference eval order)
// ||z||^2, ||c||^2 accumulated from the same LDS fragments (deterministic).
// ---------------------------------------------------------------------------
__global__ __launch_bounds__(256) void tokens_kernel(
    const float* __restrict__ Z,
    const float* __restrict__ CB,
    float* __restrict__ tokf)
{
    constexpr int BM=128, BN=128, BK=16;
    __shared__ __align__(16) float As[BK][BM+4];
    __shared__ __align__(16) float Cs[BK][BN+4];
    __shared__ float red_d[BM][16];
    __shared__ int   red_i[BM][16];

    const int tid = threadIdx.x;
    const int tx = tid & 15, ty = tid >> 4;
    const int m0 = blockIdx.x * BM;
    const int q  = tid & 3;
    const int r0 = tid >> 2;

    const float* zp0 = Z + (size_t)(m0 + r0)*256;
    const float* zp1 = zp0 + (size_t)64*256;

    float bd[8]; int bi[8]; float z2[8];
    #pragma unroll
    for (int i=0;i<8;++i){ bd[i] = FLT_MAX; bi[i] = 0; z2[i] = 0.0f; }

    for (int cb=0; cb<4; ++cb){
        const int c0 = cb * 128;
        const float* cp0 = CB + (size_t)(c0 + r0)*256;
        const float* cp1 = cp0 + (size_t)64*256;

        float acc[8][8];
        float cn[8];
        #pragma unroll
        for (int i=0;i<8;++i){
            cn[i] = 0.0f;
            #pragma unroll
            for (int j=0;j<8;++j) acc[i][j] = 0.0f;
        }

        for (int k0=0; k0<256; k0+=BK){
            const int k = k0 + q*4;
            float4 va = *(const float4*)(zp0 + k);
            float4 vb = *(const float4*)(zp1 + k);
            As[q*4+0][r0]    = va.x; As[q*4+1][r0]    = va.y;
            As[q*4+2][r0]    = va.z; As[q*4+3][r0]    = va.w;
            As[q*4+0][r0+64] = vb.x; As[q*4+1][r0+64] = vb.y;
            As[q*4+2][r0+64] = vb.z; As[q*4+3][r0+64] = vb.w;
            float4 ca = *(const float4*)(cp0 + k);
            float4 cc = *(const float4*)(cp1 + k);
            Cs[q*4+0][r0]    = ca.x; Cs[q*4+1][r0]    = ca.y;
            Cs[q*4+2][r0]    = ca.z; Cs[q*4+3][r0]    = ca.w;
            Cs[q*4+0][r0+64] = cc.x; Cs[q*4+1][r0+64] = cc.y;
            Cs[q*4+2][r0+64] = cc.z; Cs[q*4+3][r0+64] = cc.w;
            __syncthreads();
            #pragma unroll
            for (int kk=0; kk<BK; ++kk){
                float a[8], b[8];
                *(float4*)&a[0] = *(const float4*)&As[kk][ty*8];
                *(float4*)&a[4] = *(const float4*)&As[kk][ty*8+4];
                *(float4*)&b[0] = *(const float4*)&Cs[kk][tx*8];
                *(float4*)&b[4] = *(const float4*)&Cs[kk][tx*8+4];
                if (cb == 0){
                    #pragma unroll
                    for (int i=0;i<8;++i) z2[i] = fmaf(a[i], a[i], z2[i]);
                }
                #pragma unroll
                for (int j=0;j<8;++j) cn[j] = fmaf(b[j], b[j], cn[j]);
                #pragma unroll
                for (int i=0;i<8;++i)
                    #pragma unroll
                    for (int j=0;j<8;++j)
                        acc[i][j] = fmaf(a[i], b[j], acc[i][j]);
            }
            __syncthreads();
        }

        #pragma unroll
        for (int i=0;i<8;++i)
            #pragma unroll
            for (int j=0;j<8;++j){
                float dd = (z2[i] - 2.0f*acc[i][j]) + cn[j];
                int c = c0 + tx*8 + j;
                if (dd < bd[i] || (dd == bd[i] && c < bi[i])){
                    bd[i] = dd; bi[i] = c;
                }
            }
    }

    #pragma unroll
    for (int i=0;i<8;++i){
        red_d[ty*8+i][tx] = bd[i];
        red_i[ty*8+i][tx] = bi[i];
    }
    __syncthreads();
    if (tid < BM){
        float best = red_d[tid][0]; int bsti = red_i[tid][0];
        #pragma unroll
        for (int t=1;t<16;++t){
            float d = red_d[tid][t]; int ii = red_i[tid][t];
            if (d < best || (d == best && ii < bsti)){ best = d; bsti = ii; }
        }
        tokf[m0 + tid] = (float)bsti;
    }
}

// ---------------------------------------------------------------------------
// Commitment loss: sum over (z_e - codebook[tok])^2 ; atomics into loss[1].
// ---------------------------------------------------------------------------
__global__ __launch_bounds__(256) void commit_kernel(
    const float* __restrict__ Z, const float* __restrict__ CB,
    const float* __restrict__ tokf, float* __restrict__ loss)
{
    const int tid = threadIdx.x;
    size_t e0 = ((size_t)blockIdx.x*256 + tid) * 8;
    int row = (int)(e0 >> 8);
    int d   = (int)(e0 & 255);
    int g = (int)tokf[row];
    const float4* zp = (const float4*)(Z + e0);
    const float4* cp = (const float4*)(CB + (size_t)g*256 + d);
    float s = 0.0f;
    #pragma unroll
    for (int u=0; u<2; ++u){
        float4 a = zp[u], b = cp[u];
        float dx=a.x-b.x, dy=a.y-b.y, dz=a.z-b.z, dw=a.w-b.w;
        s += dx*dx + dy*dy + dz*dz + dw*dw;
    }
    #pragma unroll
    for (int off=32; off>0; off>>=1) s += __shfl_down(s, off);
    __shared__ float wsum[4];
    int lane = tid & 63, wv = tid >> 6;
    if (lane == 0) wsum[wv] = s;
    __syncthreads();
    if (tid == 0) atomicAdd(loss + 1, wsum[0]+wsum[1]+wsum[2]+wsum[3]);
}

// ---------------------------------------------------------------------------
// dec3: Y[T,48] = A @ W3^T + b3, fused un-patchify to recon + recon loss.
// 192 threads, BM=128, BN=48, microtile 8x4.
// ---------------------------------------------------------------------------
__global__ __launch_bounds__(192) void dec3_kernel(
    const float* __restrict__ Ain, const float* __restrict__ W,
    const float* __restrict__ bias, const float* __restrict__ frames,
    float* __restrict__ recon, float* __restrict__ loss)
{
    constexpr int BM=128, BK=16, K=256;
    __shared__ __align__(16) float As[BK][BM+4];
    __shared__ __align__(16) float Ws[BK][48+4];

    const int tid = threadIdx.x;
    const int tx = tid % 12, ty = tid / 12;   // 12 x 16
    const int m0 = blockIdx.x * BM;

    float acc[8][4];
    #pragma unroll
    for (int i=0;i<8;++i)
        #pragma unroll
        for (int j=0;j<4;++j) acc[i][j] = 0.0f;

    const int wq = tid & 3, wr = tid >> 2;   // wr 0..47
    const float* wp = W + (size_t)wr * K;

    for (int k0=0; k0<K; k0+=BK){
        for (int l=tid; l<512; l+=192){
            int r = l >> 2, qq = l & 3;
            float4 v = *(const float4*)(Ain + (size_t)(m0+r)*K + k0 + qq*4);
            As[qq*4+0][r]=v.x; As[qq*4+1][r]=v.y; As[qq*4+2][r]=v.z; As[qq*4+3][r]=v.w;
        }
        {
            float4 v = *(const float4*)(wp + k0 + wq*4);
            Ws[wq*4+0][wr]=v.x; Ws[wq*4+1][wr]=v.y; Ws[wq*4+2][wr]=v.z; Ws[wq*4+3][wr]=v.w;
        }
        __syncthreads();
        #pragma unroll
        for (int kk=0; kk<BK; ++kk){
            float a[8], b[4];
            *(float4*)&a[0] = *(const float4*)&As[kk][ty*8];
            *(float4*)&a[4] = *(const float4*)&As[kk][ty*8+4];
            *(float4*)&b[0] = *(const float4*)&Ws[kk][tx*4];
            #pragma unroll
            for (int i=0;i<8;++i)
                #pragma unroll
                for (int j=0;j<4;++j)
                    acc[i][j] = fmaf(a[i], b[j], acc[i][j]);
        }
        __syncthreads();
    }

    const int cbase = tx*4;
    const int ph = cbase/12, rem = cbase - ph*12;
    float4 bv = *(const float4*)(bias + cbase);
    const float sc = 2.0f/255.0f;
    float ls = 0.0f;

    #pragma unroll
    for (int i=0;i<8;++i){
        int p = m0 + ty*8 + i;
        int b = p >> 12, nl = p & 4095, hh = nl >> 6, ww = nl & 63;
        size_t addr = (size_t)(((b*256 + hh*4 + ph)*256 + ww*4)*3 + rem);
        float4 y;
        y.x = acc[i][0] + bv.x; y.y = acc[i][1] + bv.y;
        y.z = acc[i][2] + bv.z; y.w = acc[i][3] + bv.w;
        float4 f = *(const float4*)(frames + addr);
        float t0 = f.x*sc-1.0f, t1 = f.y*sc-1.0f, t2 = f.z*sc-1.0f, t3 = f.w*sc-1.0f;
        float d0 = y.x-t0, d1 = y.y-t1, d2 = y.z-t2, d3 = y.w-t3;
        ls += d0*d0 + d1*d1 + d2*d2 + d3*d3;
        *(float4*)(recon + addr) = y;
    }

    #pragma unroll
    for (int off=32; off>0; off>>=1) ls += __shfl_down(ls, off);
    __shared__ float wsum[3];
    int lane = tid & 63, wv = tid >> 6;
    if (lane == 0) wsum[wv] = ls;
    __syncthreads();
    if (tid == 0) atomicAdd(loss + 0, wsum[0]+wsum[1]+wsum[2]);
}

__global__ void finalize_kernel(float* __restrict__ loss){
    if (threadIdx.x == 0 && blockIdx.x == 0){
        loss[0] = loss[0] * (1.0f/6291456.0f);
        float c = loss[1] * (1.0f/33554432.0f);
        loss[1] = c;
        loss[2] = c;
    }
}

extern "C" void kernel_launch(void* const* d_in, const int* in_sizes, int n_in,
                              void* d_out, int out_size, void* d_ws, size_t ws_size,
                              hipStream_t stream)
{
    (void)in_sizes; (void)n_in; (void)out_size; (void)ws_size;
    const float* frames   = (const float*)d_in[0];
    const float* enc_w1   = (const float*)d_in[1];
    const float* enc_b1   = (const float*)d_in[2];
    const float* enc_w2   = (const float*)d_in[3];
    const float* enc_b2   = (const float*)d_in[4];
    const float* enc_w3   = (const float*)d_in[5];
    const float* enc_b3   = (const float*)d_in[6];
    const float* codebook = (const float*)d_in[7];
    const float* dec_w1   = (const float*)d_in[8];
    const float* dec_b1   = (const float*)d_in[9];
    const float* dec_w2   = (const float*)d_in[10];
    const float* dec_b2   = (const float*)d_in[11];
    const float* dec_w3   = (const float*)d_in[12];
    const float* dec_b3   = (const float*)d_in[13];

    float* A = (float*)d_ws;                        // [T,256]
    float* B = A + (size_t)T_ROWS * 256;            // [T,256]

    float* recon = (float*)d_out;                   // 6,291,456
    float* tokf  = recon + 6291456;                 // 131,072
    float* loss  = tokf + 131072;                   // 3 scalars (also accumulators)

    hipMemsetAsync(loss, 0, 3*sizeof(float), stream);

    dim3 blk(256), grid2(T_ROWS/128, 2);
    // encoder
    gemm_kernel<48,  true, 1><<<grid2, blk, 0, stream>>>(nullptr, frames, nullptr, nullptr, enc_w1, enc_b1, A);
    gemm_kernel<256, true, 0><<<grid2, blk, 0, stream>>>(A, nullptr, nullptr, nullptr, enc_w2, enc_b2, B);
    gemm_kernel<256, false,0><<<grid2, blk, 0, stream>>>(B, nullptr, nullptr, nullptr, enc_w3, enc_b3, A);
    // vector quantization
    tokens_kernel<<<dim3(T_ROWS/128), blk, 0, stream>>>(A, codebook, tokf);
    commit_kernel<<<dim3(16384), blk, 0, stream>>>(A, codebook, tokf, loss);
    // decoder
    gemm_kernel<256, true, 2><<<grid2, blk, 0, stream>>>(nullptr, nullptr, codebook, tokf, dec_w1, dec_b1, B);
    gemm_kernel<256, true, 0><<<grid2, blk, 0, stream>>>(B, nullptr, nullptr, nullptr, dec_w2, dec_b2, A);
    dec3_kernel<<<dim3(T_ROWS/128), dim3(192), 0, stream>>>(A, dec_w3, dec_b3, frames, recon, loss);
    finalize_kernel<<<dim3(1), dim3(64), 0, stream>>>(loss);
}

// Round 2
// 1275.338 us; speedup vs baseline: 1.3952x; 1.3952x over previous
//
#include <hip/hip_runtime.h>
#include <hip/hip_bf16.h>
#include <math.h>
#include <float.h>

#define T_ROWS 131072   // 32 * 4096 patches

typedef __attribute__((ext_vector_type(8))) short short8;
typedef __attribute__((ext_vector_type(4))) float f32x4;

__device__ __forceinline__ float gelu_f(float x){
    return 0.5f * x * (1.0f + erff(x * 0.7071067811865475f));
}
__device__ __forceinline__ float bf2f(ushort u){
    union { unsigned int i; float f; } v; v.i = ((unsigned int)u) << 16; return v.f;
}
__device__ __forceinline__ ushort f2bf(float f){
    union { float f; unsigned int i; } v; v.f = f;
    unsigned int i = v.i;
    unsigned int r = (i + 0x7fffu + ((i >> 16) & 1u)) >> 16;
    return (ushort)r;
}

// ---------------------------------------------------------------------------
// f32 tiled GEMM: C[M,256] = act(A[M,K] @ W[256,K]^T + b)
// BM=128, BN=128, BK=16, 256 threads, 8x8 microtile in 2x2 split-4 layout
// (reads at [tx*4] and [64+tx*4] -> 16B stride across 16 lanes = conflict-free)
// LOADER: 0 = plain f32 A, 1 = patchify+normalize from frames (K==48)
// ---------------------------------------------------------------------------
template<int K, bool GELU, int LOADER>
__global__ __launch_bounds__(256) void gemm_kernel(
    const float* __restrict__ Ain,
    const float* __restrict__ frames,
    const float* __restrict__ W,
    const float* __restrict__ bias,
    float* __restrict__ Cout)
{
    constexpr int BM=128, BN=128, BK=16;
    __shared__ __align__(16) float As[BK][BM+4];
    __shared__ __align__(16) float Ws[BK][BN+4];

    const int tid = threadIdx.x;
    const int tx = tid & 15, ty = tid >> 4;
    const int m0 = blockIdx.x * BM;
    const int c0 = blockIdx.y * BN;

    const int q  = tid & 3;      // k-quad within BK
    const int r0 = tid >> 2;     // 0..63 ; rows r0 and r0+64

    const float* aptr0 = nullptr;
    const float* aptr1 = nullptr;
    int base0 = 0, base1 = 0;
    if constexpr (LOADER == 0){
        aptr0 = Ain + (size_t)(m0 + r0) * K;
        aptr1 = aptr0 + (size_t)64 * K;
    } else {
        int p0 = m0 + r0;
        int b = p0 >> 12, nl = p0 & 4095, hh = nl >> 6, ww = nl & 63;
        base0 = ((b*256 + hh*4)*256 + ww*4)*3;
        int p1 = p0 + 64;
        b = p1 >> 12; nl = p1 & 4095; hh = nl >> 6; ww = nl & 63;
        base1 = ((b*256 + hh*4)*256 + ww*4)*3;
    }
    const float* wptr0 = W + (size_t)(c0 + r0) * K;
    const float* wptr1 = wptr0 + (size_t)64 * K;

    float acc[8][8];
    #pragma unroll
    for (int i=0;i<8;++i)
        #pragma unroll
        for (int j=0;j<8;++j) acc[i][j] = 0.0f;

    for (int k0 = 0; k0 < K; k0 += BK){
        const int k = k0 + q*4;
        float4 va, vb;
        if constexpr (LOADER == 1){
            const int ph = k / 12, rem = k - ph*12;
            va = *(const float4*)(frames + base0 + ph*768 + rem);
            vb = *(const float4*)(frames + base1 + ph*768 + rem);
            const float sc = 2.0f/255.0f;
            va.x = va.x*sc - 1.0f; va.y = va.y*sc - 1.0f;
            va.z = va.z*sc - 1.0f; va.w = va.w*sc - 1.0f;
            vb.x = vb.x*sc - 1.0f; vb.y = vb.y*sc - 1.0f;
            vb.z = vb.z*sc - 1.0f; vb.w = vb.w*sc - 1.0f;
        } else {
            va = *(const float4*)(aptr0 + k);
            vb = *(const float4*)(aptr1 + k);
        }
        As[q*4+0][r0]    = va.x; As[q*4+1][r0]    = va.y;
        As[q*4+2][r0]    = va.z; As[q*4+3][r0]    = va.w;
        As[q*4+0][r0+64] = vb.x; As[q*4+1][r0+64] = vb.y;
        As[q*4+2][r0+64] = vb.z; As[q*4+3][r0+64] = vb.w;

        float4 wa = *(const float4*)(wptr0 + k);
        float4 wb = *(const float4*)(wptr1 + k);
        Ws[q*4+0][r0]    = wa.x; Ws[q*4+1][r0]    = wa.y;
        Ws[q*4+2][r0]    = wa.z; Ws[q*4+3][r0]    = wa.w;
        Ws[q*4+0][r0+64] = wb.x; Ws[q*4+1][r0+64] = wb.y;
        Ws[q*4+2][r0+64] = wb.z; Ws[q*4+3][r0+64] = wb.w;

        __syncthreads();
        #pragma unroll
        for (int kk=0; kk<BK; ++kk){
            float a[8], b[8];
            *(float4*)&a[0] = *(const float4*)&As[kk][ty*4];
            *(float4*)&a[4] = *(const float4*)&As[kk][64+ty*4];
            *(float4*)&b[0] = *(const float4*)&Ws[kk][tx*4];
            *(float4*)&b[4] = *(const float4*)&Ws[kk][64+tx*4];
            #pragma unroll
            for (int i=0;i<8;++i)
                #pragma unroll
                for (int j=0;j<8;++j)
                    acc[i][j] = fmaf(a[i], b[j], acc[i][j]);
        }
        __syncthreads();
    }

    float bj[8];
    *(float4*)&bj[0] = *(const float4*)(bias + c0 + tx*4);
    *(float4*)&bj[4] = *(const float4*)(bias + c0 + 64 + tx*4);
    #pragma unroll
    for (int i=0;i<8;++i){
        const int row = m0 + ((i<4) ? (ty*4+i) : (64+ty*4+i-4));
        float o[8];
        #pragma unroll
        for (int j=0;j<8;++j){
            float x = acc[i][j] + bj[j];
            o[j] = GELU ? gelu_f(x) : x;
        }
        float* dst = Cout + (size_t)row*256 + c0 + tx*4;
        *(float4*)dst      = *(const float4*)&o[0];
        *(float4*)(dst+64) = *(const float4*)&o[4];
    }
}

// ---------------------------------------------------------------------------
// ||c||^2 per code: one wave per code
// ---------------------------------------------------------------------------
__global__ __launch_bounds__(256) void cnorm_kernel(
    const float* __restrict__ cb, float* __restrict__ cn)
{
    const int lane = threadIdx.x & 63;
    const int code = blockIdx.x*4 + (threadIdx.x >> 6);
    float4 v = ((const float4*)(cb + (size_t)code*256))[lane];
    float s = v.x*v.x + v.y*v.y + v.z*v.z + v.w*v.w;
    #pragma unroll
    for (int m=1; m<64; m<<=1) s += __shfl_xor(s, m);
    if (lane == 0) cn[code] = s;
}

// ---------------------------------------------------------------------------
// tokens GEMM: per block 128 rows x 128 codes, dist = cn[c] - 2*dot(z,c)
// (||z||^2 dropped — constant per row, cancels in argmin)
// partial (best, idx) per (row, colblock) -> ws; shuffle-reduce over tx.
// ---------------------------------------------------------------------------
__global__ __launch_bounds__(256) void tokens_gemm(
    const float* __restrict__ Z,
    const float* __restrict__ CB,
    const float* __restrict__ cn,
    float2* __restrict__ partials)
{
    constexpr int BM=128, BN=128, BK=16;
    __shared__ __align__(16) float As[BK][BM+4];
    __shared__ __align__(16) float Cs[BK][BN+4];

    const int tid = threadIdx.x;
    const int tx = tid & 15, ty = tid >> 4;
    const int m0 = blockIdx.x * BM;
    const int c0 = blockIdx.y * BN;
    const int q  = tid & 3;
    const int r0 = tid >> 2;

    const float* zp0 = Z + (size_t)(m0 + r0)*256;
    const float* zp1 = zp0 + (size_t)64*256;
    const float* cp0 = CB + (size_t)(c0 + r0)*256;
    const float* cp1 = cp0 + (size_t)64*256;

    float acc[8][8];
    #pragma unroll
    for (int i=0;i<8;++i)
        #pragma unroll
        for (int j=0;j<8;++j) acc[i][j] = 0.0f;

    for (int k0=0; k0<256; k0+=BK){
        const int k = k0 + q*4;
        float4 va = *(const float4*)(zp0 + k);
        float4 vb = *(const float4*)(zp1 + k);
        As[q*4+0][r0]    = va.x; As[q*4+1][r0]    = va.y;
        As[q*4+2][r0]    = va.z; As[q*4+3][r0]    = va.w;
        As[q*4+0][r0+64] = vb.x; As[q*4+1][r0+64] = vb.y;
        As[q*4+2][r0+64] = vb.z; As[q*4+3][r0+64] = vb.w;
        float4 ca = *(const float4*)(cp0 + k);
        float4 cc = *(const float4*)(cp1 + k);
        Cs[q*4+0][r0]    = ca.x; Cs[q*4+1][r0]    = ca.y;
        Cs[q*4+2][r0]    = ca.z; Cs[q*4+3][r0]    = ca.w;
        Cs[q*4+0][r0+64] = cc.x; Cs[q*4+1][r0+64] = cc.y;
        Cs[q*4+2][r0+64] = cc.z; Cs[q*4+3][r0+64] = cc.w;
        __syncthreads();
        #pragma unroll
        for (int kk=0; kk<BK; ++kk){
            float a[8], b[8];
            *(float4*)&a[0] = *(const float4*)&As[kk][ty*4];
            *(float4*)&a[4] = *(const float4*)&As[kk][64+ty*4];
            *(float4*)&b[0] = *(const float4*)&Cs[kk][tx*4];
            *(float4*)&b[4] = *(const float4*)&Cs[kk][64+tx*4];
            #pragma unroll
            for (int i=0;i<8;++i)
                #pragma unroll
                for (int j=0;j<8;++j)
                    acc[i][j] = fmaf(a[i], b[j], acc[i][j]);
        }
        __syncthreads();
    }

    float cnl[8];
    *(float4*)&cnl[0] = *(const float4*)(cn + c0 + tx*4);
    *(float4*)&cnl[4] = *(const float4*)(cn + c0 + 64 + tx*4);

    #pragma unroll
    for (int i=0;i<8;++i){
        const int row = m0 + ((i<4) ? (ty*4+i) : (64+ty*4+i-4));
        float best = FLT_MAX; int bi = 0x3fffffff;
        #pragma unroll
        for (int j=0;j<8;++j){
            const int c = c0 + ((j<4) ? (tx*4+j) : (64+tx*4+j-4));
            float v = cnl[j] - 2.0f*acc[i][j];
            if (v < best || (v == best && c < bi)){ best = v; bi = c; }
        }
        #pragma unroll
        for (int m=1; m<16; m<<=1){
            float od = __shfl_xor(best, m);
            int   oi = __shfl_xor(bi, m);
            if (od < best || (od == best && oi < bi)){ best = od; bi = oi; }
        }
        if (tx == 0)
            partials[(size_t)row*4 + blockIdx.y] = make_float2(best, (float)bi);
    }
}

__global__ __launch_bounds__(256) void token_reduce(
    const float2* __restrict__ partials, float* __restrict__ tokf)
{
    const int r = blockIdx.x*256 + threadIdx.x;
    float2 p = partials[(size_t)r*4];
    float best = p.x; int bi = (int)p.y;
    #pragma unroll
    for (int t=1; t<4; ++t){
        p = partials[(size_t)r*4 + t];
        int ii = (int)p.y;
        if (p.x < best || (p.x == best && ii < bi)){ best = p.x; bi = ii; }
    }
    tokf[r] = (float)bi;
}

// ---------------------------------------------------------------------------
// Commitment loss: sum over (z_e - codebook[tok])^2 ; atomics into loss[1].
// ---------------------------------------------------------------------------
__global__ __launch_bounds__(256) void commit_kernel(
    const float* __restrict__ Z, const float* __restrict__ CB,
    const float* __restrict__ tokf, float* __restrict__ loss)
{
    const int tid = threadIdx.x;
    size_t e0 = ((size_t)blockIdx.x*256 + tid) * 8;
    int row = (int)(e0 >> 8);
    int d   = (int)(e0 & 255);
    int g = (int)tokf[row];
    const float4* zp = (const float4*)(Z + e0);
    const float4* cp = (const float4*)(CB + (size_t)g*256 + d);
    float s = 0.0f;
    #pragma unroll
    for (int u=0; u<2; ++u){
        float4 a = zp[u], b = cp[u];
        float dx=a.x-b.x, dy=a.y-b.y, dz=a.z-b.z, dw=a.w-b.w;
        s += dx*dx + dy*dy + dz*dz + dw*dw;
    }
    #pragma unroll
    for (int off=32; off>0; off>>=1) s += __shfl_down(s, off);
    __shared__ float wsum[4];
    int lane = tid & 63, wv = tid >> 6;
    if (lane == 0) wsum[wv] = s;
    __syncthreads();
    if (tid == 0) atomicAdd(loss + 1, wsum[0]+wsum[1]+wsum[2]+wsum[3]);
}

// ---------------------------------------------------------------------------
// weight f32 -> bf16 conversion (dec_w1, dec_w2)
// ---------------------------------------------------------------------------
__global__ __launch_bounds__(256) void convw_kernel(
    const float* __restrict__ w1, const float* __restrict__ w2,
    ushort* __restrict__ o1, ushort* __restrict__ o2)
{
    const int i = (blockIdx.x*256 + threadIdx.x)*4;
    float4 a = *(const float4*)(w1 + i);
    ushort4 u; u.x=f2bf(a.x); u.y=f2bf(a.y); u.z=f2bf(a.z); u.w=f2bf(a.w);
    *(ushort4*)(o1 + i) = u;
    float4 b = *(const float4*)(w2 + i);
    ushort4 v; v.x=f2bf(b.x); v.y=f2bf(b.y); v.z=f2bf(b.z); v.w=f2bf(b.w);
    *(ushort4*)(o2 + i) = v;
}

// ---------------------------------------------------------------------------
// bf16 MFMA GEMM: Y[M,256] = gelu(A[M,256] @ W[256,256]^T + b) in bf16
// 128x128 tile, 4 waves (2x2 of 64x64), 16x16x32 MFMA, BK=32.
// LOADER: 0 = plain bf16 A, 1 = gather codebook rows (f32->bf16) via tokens.
// ---------------------------------------------------------------------------
template<int LOADER>
__global__ __launch_bounds__(256) void mfma_gemm(
    const ushort* __restrict__ Abf,
    const float* __restrict__ codebook,
    const float* __restrict__ tokf,
    const ushort* __restrict__ Wbf,
    const float* __restrict__ bias,
    ushort* __restrict__ Ybf)
{
    __shared__ __align__(16) ushort Al[128][40];
    __shared__ __align__(16) ushort Wl[128][40];

    const int tid = threadIdx.x;
    const int m0 = blockIdx.x * 128;
    const int n0 = blockIdx.y * 128;
    const int srow = tid >> 1, shalf = (tid & 1) * 16;
    const int lane = tid & 63;
    const int w = tid >> 6;
    const int wm = (w >> 1) * 64, wn = (w & 1) * 64;
    const int lr = lane & 15, lg = lane >> 4;

    const float* gsrc = nullptr;
    const ushort* asrc = nullptr;
    if constexpr (LOADER == 1){
        int g = (int)tokf[m0 + srow];
        gsrc = codebook + (size_t)g*256 + shalf;
    } else {
        asrc = Abf + (size_t)(m0 + srow)*256 + shalf;
    }
    const ushort* wsrc = Wbf + (size_t)(n0 + srow)*256 + shalf;

    f32x4 acc[4][4];
    #pragma unroll
    for (int mi=0;mi<4;++mi)
        #pragma unroll
        for (int ni=0;ni<4;++ni)
            acc[mi][ni] = (f32x4){0.f,0.f,0.f,0.f};

    for (int k0=0; k0<256; k0+=32){
        if constexpr (LOADER == 1){
            float4 f0 = *(const float4*)(gsrc + k0);
            float4 f1 = *(const float4*)(gsrc + k0 + 4);
            float4 f2 = *(const float4*)(gsrc + k0 + 8);
            float4 f3 = *(const float4*)(gsrc + k0 + 12);
            ushort t[16];
            t[0]=f2bf(f0.x); t[1]=f2bf(f0.y); t[2]=f2bf(f0.z); t[3]=f2bf(f0.w);
            t[4]=f2bf(f1.x); t[5]=f2bf(f1.y); t[6]=f2bf(f1.z); t[7]=f2bf(f1.w);
            t[8]=f2bf(f2.x); t[9]=f2bf(f2.y); t[10]=f2bf(f2.z); t[11]=f2bf(f2.w);
            t[12]=f2bf(f3.x); t[13]=f2bf(f3.y); t[14]=f2bf(f3.z); t[15]=f2bf(f3.w);
            *(uint4*)&Al[srow][shalf]   = *(const uint4*)&t[0];
            *(uint4*)&Al[srow][shalf+8] = *(const uint4*)&t[8];
        } else {
            *(uint4*)&Al[srow][shalf]   = *(const uint4*)(asrc + k0);
            *(uint4*)&Al[srow][shalf+8] = *(const uint4*)(asrc + k0 + 8);
        }
        *(uint4*)&Wl[srow][shalf]   = *(const uint4*)(wsrc + k0);
        *(uint4*)&Wl[srow][shalf+8] = *(const uint4*)(wsrc + k0 + 8);
        __syncthreads();

        short8 af[4], bfr[4];
        #pragma unroll
        for (int mi=0;mi<4;++mi)
            af[mi] = *(const short8*)&Al[wm + mi*16 + lr][lg*8];
        #pragma unroll
        for (int ni=0;ni<4;++ni)
            bfr[ni] = *(const short8*)&Wl[wn + ni*16 + lr][lg*8];
        #pragma unroll
        for (int mi=0;mi<4;++mi)
            #pragma unroll
            for (int ni=0;ni<4;++ni)
                acc[mi][ni] = __builtin_amdgcn_mfma_f32_16x16x32_bf16(
                    af[mi], bfr[ni], acc[mi][ni], 0, 0, 0);
        __syncthreads();
    }

    float bn[4];
    #pragma unroll
    for (int ni=0;ni<4;++ni) bn[ni] = bias[n0 + wn + ni*16 + lr];
    #pragma unroll
    for (int mi=0;mi<4;++mi)
        #pragma unroll
        for (int ni=0;ni<4;++ni)
            #pragma unroll
            for (int r=0;r<4;++r){
                int row = m0 + wm + mi*16 + lg*4 + r;
                float v = acc[mi][ni][r] + bn[ni];
                v = gelu_f(v);
                Ybf[(size_t)row*256 + n0 + wn + ni*16 + lr] = f2bf(v);
            }
}

// ---------------------------------------------------------------------------
// dec3: Y[T,48] = A_bf16 @ W3^T + b3 (f32 math), fused un-patchify + loss.
// ---------------------------------------------------------------------------
__global__ __launch_bounds__(192) void dec3_kernel(
    const ushort* __restrict__ Ain, const float* __restrict__ W,
    const float* __restrict__ bias, const float* __restrict__ frames,
    float* __restrict__ recon, float* __restrict__ loss)
{
    constexpr int BM=128, BK=16, K=256;
    __shared__ __align__(16) float As[BK][BM+4];
    __shared__ __align__(16) float Ws[BK][48+4];

    const int tid = threadIdx.x;
    const int tx = tid % 12, ty = tid / 12;   // 12 x 16
    const int m0 = blockIdx.x * BM;

    float acc[8][4];
    #pragma unroll
    for (int i=0;i<8;++i)
        #pragma unroll
        for (int j=0;j<4;++j) acc[i][j] = 0.0f;

    const int wq = tid & 3, wr = tid >> 2;   // wr 0..47
    const float* wp = W + (size_t)wr * K;

    for (int k0=0; k0<K; k0+=BK){
        for (int l=tid; l<512; l+=192){
            int r = l >> 2, qq = l & 3;
            ushort4 v = *(const ushort4*)(Ain + (size_t)(m0+r)*K + k0 + qq*4);
            As[qq*4+0][r]=bf2f(v.x); As[qq*4+1][r]=bf2f(v.y);
            As[qq*4+2][r]=bf2f(v.z); As[qq*4+3][r]=bf2f(v.w);
        }
        if (tid < 192){
            float4 v = *(const float4*)(wp + k0 + wq*4);
            Ws[wq*4+0][wr]=v.x; Ws[wq*4+1][wr]=v.y; Ws[wq*4+2][wr]=v.z; Ws[wq*4+3][wr]=v.w;
        }
        __syncthreads();
        #pragma unroll
        for (int kk=0; kk<BK; ++kk){
            float a[8], b[4];
            *(float4*)&a[0] = *(const float4*)&As[kk][ty*8];
            *(float4*)&a[4] = *(const float4*)&As[kk][ty*8+4];
            *(float4*)&b[0] = *(const float4*)&Ws[kk][tx*4];
            #pragma unroll
            for (int i=0;i<8;++i)
                #pragma unroll
                for (int j=0;j<4;++j)
                    acc[i][j] = fmaf(a[i], b[j], acc[i][j]);
        }
        __syncthreads();
    }

    const int cbase = tx*4;
    const int ph = cbase/12, rem = cbase - ph*12;
    float4 bv = *(const float4*)(bias + cbase);
    const float sc = 2.0f/255.0f;
    float ls = 0.0f;

    #pragma unroll
    for (int i=0;i<8;++i){
        int p = m0 + ty*8 + i;
        int b = p >> 12, nl = p & 4095, hh = nl >> 6, ww = nl & 63;
        size_t addr = (size_t)(((b*256 + hh*4 + ph)*256 + ww*4)*3 + rem);
        float4 y;
        y.x = acc[i][0] + bv.x; y.y = acc[i][1] + bv.y;
        y.z = acc[i][2] + bv.z; y.w = acc[i][3] + bv.w;
        float4 f = *(const float4*)(frames + addr);
        float t0 = f.x*sc-1.0f, t1 = f.y*sc-1.0f, t2 = f.z*sc-1.0f, t3 = f.w*sc-1.0f;
        float d0 = y.x-t0, d1 = y.y-t1, d2 = y.z-t2, d3 = y.w-t3;
        ls += d0*d0 + d1*d1 + d2*d2 + d3*d3;
        *(float4*)(recon + addr) = y;
    }

    #pragma unroll
    for (int off=32; off>0; off>>=1) ls += __shfl_down(ls, off);
    __shared__ float wsum[3];
    int lane = tid & 63, wv = tid >> 6;
    if (lane == 0) wsum[wv] = ls;
    __syncthreads();
    if (tid == 0) atomicAdd(loss + 0, wsum[0]+wsum[1]+wsum[2]);
}

__global__ void finalize_kernel(float* __restrict__ loss){
    if (threadIdx.x == 0 && blockIdx.x == 0){
        loss[0] = loss[0] * (1.0f/6291456.0f);
        float c = loss[1] * (1.0f/33554432.0f);
        loss[1] = c;
        loss[2] = c;
    }
}

extern "C" void kernel_launch(void* const* d_in, const int* in_sizes, int n_in,
                              void* d_out, int out_size, void* d_ws, size_t ws_size,
                              hipStream_t stream)
{
    (void)in_sizes; (void)n_in; (void)out_size; (void)ws_size;
    const float* frames   = (const float*)d_in[0];
    const float* enc_w1   = (const float*)d_in[1];
    const float* enc_b1   = (const float*)d_in[2];
    const float* enc_w2   = (const float*)d_in[3];
    const float* enc_b2   = (const float*)d_in[4];
    const float* enc_w3   = (const float*)d_in[5];
    const float* enc_b3   = (const float*)d_in[6];
    const float* codebook = (const float*)d_in[7];
    const float* dec_w1   = (const float*)d_in[8];
    const float* dec_b1   = (const float*)d_in[9];
    const float* dec_w2   = (const float*)d_in[10];
    const float* dec_b2   = (const float*)d_in[11];
    const float* dec_w3   = (const float*)d_in[12];
    const float* dec_b3   = (const float*)d_in[13];

    float*  A    = (float*)d_ws;                       // [T,256] f32
    float*  Bws  = A + (size_t)T_ROWS * 256;           // [T,256] f32 region
    // sub-allocations inside B region (time-disjoint with enc2/enc3 use):
    float2* partials = (float2*)Bws;                   // 131072*4 float2 (4 MB)
    ushort* Y1   = (ushort*)Bws;                       // [T,256] bf16 (67 MB)
    ushort* Y2   = (ushort*)A;                         // [T,256] bf16 (reuses A)
    float*  cn   = Bws + 33554432 - 1024;              // 512 floats
    ushort* w1b  = (ushort*)(Bws + 33554432 - 1024 - 65536);
    ushort* w2b  = w1b + 65536;

    float* recon = (float*)d_out;                      // 6,291,456
    float* tokf  = recon + 6291456;                    // 131,072
    float* loss  = tokf + 131072;                      // 3 scalars

    hipMemsetAsync(loss, 0, 3*sizeof(float), stream);

    dim3 blk(256), grid2(T_ROWS/128, 2);
    // encoder (f32 — token path must stay at f32 noise level)
    gemm_kernel<48,  true, 1><<<grid2, blk, 0, stream>>>(nullptr, frames, enc_w1, enc_b1, A);
    gemm_kernel<256, true, 0><<<grid2, blk, 0, stream>>>(A, nullptr, enc_w2, enc_b2, Bws);
    gemm_kernel<256, false,0><<<grid2, blk, 0, stream>>>(Bws, nullptr, enc_w3, enc_b3, A);
    // vector quantization
    cnorm_kernel<<<dim3(128), blk, 0, stream>>>(codebook, cn);
    tokens_gemm<<<dim3(T_ROWS/128, 4), blk, 0, stream>>>(A, codebook, cn, partials);
    token_reduce<<<dim3(T_ROWS/256), blk, 0, stream>>>(partials, tokf);
    commit_kernel<<<dim3(16384), blk, 0, stream>>>(A, codebook, tokf, loss);
    // decoder (bf16 MFMA)
    convw_kernel<<<dim3(64), blk, 0, stream>>>(dec_w1, dec_w2, w1b, w2b);
    mfma_gemm<1><<<grid2, blk, 0, stream>>>(nullptr, codebook, tokf, w1b, dec_b1, Y1);
    mfma_gemm<0><<<grid2, blk, 0, stream>>>(Y1, nullptr, nullptr, w2b, dec_b2, Y2);
    dec3_kernel<<<dim3(T_ROWS/128), dim3(192), 0, stream>>>(Y2, dec_w3, dec_b3, frames, recon, loss);
    finalize_kernel<<<dim3(1), dim3(64), 0, stream>>>(loss);
}

// Round 3
// 1029.368 us; speedup vs baseline: 1.7285x; 1.2390x over previous
//
#include <hip/hip_runtime.h>
#include <hip/hip_bf16.h>
#include <math.h>
#include <float.h>
#include <limits.h>

#define T_ROWS 131072   // 32 * 4096 patches

typedef __attribute__((ext_vector_type(8))) short short8;
typedef __attribute__((ext_vector_type(4))) float f32x4;

__device__ __forceinline__ float gelu_f(float x){
    return 0.5f * x * (1.0f + erff(x * 0.7071067811865475f));
}
__device__ __forceinline__ float bf2f(ushort u){
    union { unsigned int i; float f; } v; v.i = ((unsigned int)u) << 16; return v.f;
}
__device__ __forceinline__ ushort f2bf(float f){
    union { float f; unsigned int i; } v; v.f = f;
    unsigned int i = v.i;
    unsigned int r = (i + 0x7fffu + ((i >> 16) & 1u)) >> 16;
    return (ushort)r;
}

// ---------------------------------------------------------------------------
// f32 tiled GEMM: C[M,256] = act(A[M,K] @ W[256,K]^T + b)
// LOADER: 0 = plain f32 A, 1 = patchify+normalize from frames (K==48)
// ---------------------------------------------------------------------------
template<int K, bool GELU, int LOADER>
__global__ __launch_bounds__(256) void gemm_kernel(
    const float* __restrict__ Ain,
    const float* __restrict__ frames,
    const float* __restrict__ W,
    const float* __restrict__ bias,
    float* __restrict__ Cout)
{
    constexpr int BM=128, BN=128, BK=16;
    __shared__ __align__(16) float As[BK][BM+4];
    __shared__ __align__(16) float Ws[BK][BN+4];

    const int tid = threadIdx.x;
    const int tx = tid & 15, ty = tid >> 4;
    const int m0 = blockIdx.x * BM;
    const int c0 = blockIdx.y * BN;

    const int q  = tid & 3;
    const int r0 = tid >> 2;

    const float* aptr0 = nullptr;
    const float* aptr1 = nullptr;
    int base0 = 0, base1 = 0;
    if constexpr (LOADER == 0){
        aptr0 = Ain + (size_t)(m0 + r0) * K;
        aptr1 = aptr0 + (size_t)64 * K;
    } else {
        int p0 = m0 + r0;
        int b = p0 >> 12, nl = p0 & 4095, hh = nl >> 6, ww = nl & 63;
        base0 = ((b*256 + hh*4)*256 + ww*4)*3;
        int p1 = p0 + 64;
        b = p1 >> 12; nl = p1 & 4095; hh = nl >> 6; ww = nl & 63;
        base1 = ((b*256 + hh*4)*256 + ww*4)*3;
    }
    const float* wptr0 = W + (size_t)(c0 + r0) * K;
    const float* wptr1 = wptr0 + (size_t)64 * K;

    float acc[8][8];
    #pragma unroll
    for (int i=0;i<8;++i)
        #pragma unroll
        for (int j=0;j<8;++j) acc[i][j] = 0.0f;

    for (int k0 = 0; k0 < K; k0 += BK){
        const int k = k0 + q*4;
        float4 va, vb;
        if constexpr (LOADER == 1){
            const int ph = k / 12, rem = k - ph*12;
            va = *(const float4*)(frames + base0 + ph*768 + rem);
            vb = *(const float4*)(frames + base1 + ph*768 + rem);
            const float sc = 2.0f/255.0f;
            va.x = va.x*sc - 1.0f; va.y = va.y*sc - 1.0f;
            va.z = va.z*sc - 1.0f; va.w = va.w*sc - 1.0f;
            vb.x = vb.x*sc - 1.0f; vb.y = vb.y*sc - 1.0f;
            vb.z = vb.z*sc - 1.0f; vb.w = vb.w*sc - 1.0f;
        } else {
            va = *(const float4*)(aptr0 + k);
            vb = *(const float4*)(aptr1 + k);
        }
        As[q*4+0][r0]    = va.x; As[q*4+1][r0]    = va.y;
        As[q*4+2][r0]    = va.z; As[q*4+3][r0]    = va.w;
        As[q*4+0][r0+64] = vb.x; As[q*4+1][r0+64] = vb.y;
        As[q*4+2][r0+64] = vb.z; As[q*4+3][r0+64] = vb.w;

        float4 wa = *(const float4*)(wptr0 + k);
        float4 wb = *(const float4*)(wptr1 + k);
        Ws[q*4+0][r0]    = wa.x; Ws[q*4+1][r0]    = wa.y;
        Ws[q*4+2][r0]    = wa.z; Ws[q*4+3][r0]    = wa.w;
        Ws[q*4+0][r0+64] = wb.x; Ws[q*4+1][r0+64] = wb.y;
        Ws[q*4+2][r0+64] = wb.z; Ws[q*4+3][r0+64] = wb.w;

        __syncthreads();
        #pragma unroll
        for (int kk=0; kk<BK; ++kk){
            float a[8], b[8];
            *(float4*)&a[0] = *(const float4*)&As[kk][ty*4];
            *(float4*)&a[4] = *(const float4*)&As[kk][64+ty*4];
            *(float4*)&b[0] = *(const float4*)&Ws[kk][tx*4];
            *(float4*)&b[4] = *(const float4*)&Ws[kk][64+tx*4];
            #pragma unroll
            for (int i=0;i<8;++i)
                #pragma unroll
                for (int j=0;j<8;++j)
                    acc[i][j] = fmaf(a[i], b[j], acc[i][j]);
        }
        __syncthreads();
    }

    float bj[8];
    *(float4*)&bj[0] = *(const float4*)(bias + c0 + tx*4);
    *(float4*)&bj[4] = *(const float4*)(bias + c0 + 64 + tx*4);
    #pragma unroll
    for (int i=0;i<8;++i){
        const int row = m0 + ((i<4) ? (ty*4+i) : (64+ty*4+i-4));
        float o[8];
        #pragma unroll
        for (int j=0;j<8;++j){
            float x = acc[i][j] + bj[j];
            o[j] = GELU ? gelu_f(x) : x;
        }
        float* dst = Cout + (size_t)row*256 + c0 + tx*4;
        *(float4*)dst      = *(const float4*)&o[0];
        *(float4*)(dst+64) = *(const float4*)&o[4];
    }
}

// ---------------------------------------------------------------------------
// z_e f32 -> bf16 (for the approximate MFMA distance pass)
// ---------------------------------------------------------------------------
__global__ __launch_bounds__(256) void zconv_kernel(
    const float* __restrict__ Z, ushort* __restrict__ Zb)
{
    size_t i = ((size_t)blockIdx.x*256 + threadIdx.x)*8;
    float4 a = *(const float4*)(Z + i);
    float4 b = *(const float4*)(Z + i + 4);
    ushort t[8];
    t[0]=f2bf(a.x); t[1]=f2bf(a.y); t[2]=f2bf(a.z); t[3]=f2bf(a.w);
    t[4]=f2bf(b.x); t[5]=f2bf(b.y); t[6]=f2bf(b.z); t[7]=f2bf(b.w);
    *(uint4*)(Zb + i) = *(const uint4*)t;
}

// ---------------------------------------------------------------------------
// ||c||^2 per code (f32 exact) + bf16 codebook copy
// ---------------------------------------------------------------------------
__global__ __launch_bounds__(256) void cnorm_kernel(
    const float* __restrict__ cb, float* __restrict__ cn,
    ushort* __restrict__ cbb)
{
    const int lane = threadIdx.x & 63;
    const int code = blockIdx.x*4 + (threadIdx.x >> 6);
    float4 v = ((const float4*)(cb + (size_t)code*256))[lane];
    ushort4 u; u.x=f2bf(v.x); u.y=f2bf(v.y); u.z=f2bf(v.z); u.w=f2bf(v.w);
    *(ushort4*)(cbb + (size_t)code*256 + lane*4) = u;
    float s = v.x*v.x + v.y*v.y + v.z*v.z + v.w*v.w;
    #pragma unroll
    for (int m=1; m<64; m<<=1) s += __shfl_xor(s, m);
    if (lane == 0) cn[code] = s;
}

#define INSERT2(dv, iv) do { \
    float _d = (dv); int _i = (iv); \
    if (_d < b1 || (_d == b1 && _i < i1)){ b2=b1; i2=i1; b1=_d; i1=_i; } \
    else if (_d < b2 || (_d == b2 && _i < i2)){ b2=_d; i2=_i; } \
} while(0)

// ---------------------------------------------------------------------------
// Approximate distance pass (bf16 MFMA). Per block: 128 rows x 128 codes.
// d~ = cn[c] - 2*mfma_dot(z,c). Tracks per-row top-2 per 64-col half,
// writes 4 candidate INDICES per (row, colblock) -> 16 candidates/row.
// ---------------------------------------------------------------------------
__global__ __launch_bounds__(256) void tokens_mfma(
    const ushort* __restrict__ Zb, const ushort* __restrict__ CBb,
    const float* __restrict__ cn, float4* __restrict__ partials)
{
    __shared__ __align__(16) ushort Al[128][40];
    __shared__ __align__(16) ushort Wl[128][40];
    __shared__ float2 ptop[128][2];

    const int tid = threadIdx.x;
    const int m0 = blockIdx.x * 128;
    const int n0 = blockIdx.y * 128;
    const int srow = tid >> 1, shalf = (tid & 1) * 16;
    const int lane = tid & 63;
    const int w = tid >> 6;
    const int wm = (w >> 1) * 64, wn = (w & 1) * 64;
    const int lr = lane & 15, lg = lane >> 4;

    const ushort* asrc = Zb  + (size_t)(m0 + srow)*256 + shalf;
    const ushort* wsrc = CBb + (size_t)(n0 + srow)*256 + shalf;

    f32x4 acc[4][4];
    #pragma unroll
    for (int mi=0;mi<4;++mi)
        #pragma unroll
        for (int ni=0;ni<4;++ni)
            acc[mi][ni] = (f32x4){0.f,0.f,0.f,0.f};

    for (int k0=0; k0<256; k0+=32){
        *(uint4*)&Al[srow][shalf]   = *(const uint4*)(asrc + k0);
        *(uint4*)&Al[srow][shalf+8] = *(const uint4*)(asrc + k0 + 8);
        *(uint4*)&Wl[srow][shalf]   = *(const uint4*)(wsrc + k0);
        *(uint4*)&Wl[srow][shalf+8] = *(const uint4*)(wsrc + k0 + 8);
        __syncthreads();

        short8 af[4], bfr[4];
        #pragma unroll
        for (int mi=0;mi<4;++mi)
            af[mi] = *(const short8*)&Al[wm + mi*16 + lr][lg*8];
        #pragma unroll
        for (int ni=0;ni<4;++ni)
            bfr[ni] = *(const short8*)&Wl[wn + ni*16 + lr][lg*8];
        #pragma unroll
        for (int mi=0;mi<4;++mi)
            #pragma unroll
            for (int ni=0;ni<4;++ni)
                acc[mi][ni] = __builtin_amdgcn_mfma_f32_16x16x32_bf16(
                    af[mi], bfr[ni], acc[mi][ni], 0, 0, 0);
        __syncthreads();
    }

    float cnl[4];
    #pragma unroll
    for (int ni=0;ni<4;++ni) cnl[ni] = cn[n0 + wn + ni*16 + lr];

    #pragma unroll
    for (int mi=0;mi<4;++mi)
        #pragma unroll
        for (int r=0;r<4;++r){
            float b1 = FLT_MAX, b2 = FLT_MAX;
            int   i1 = INT_MAX, i2 = INT_MAX;
            #pragma unroll
            for (int ni=0;ni<4;++ni){
                float d = cnl[ni] - 2.0f*acc[mi][ni][r];
                int col = n0 + wn + ni*16 + lr;
                INSERT2(d, col);
            }
            #pragma unroll
            for (int m=1; m<16; m<<=1){
                float o1 = __shfl_xor(b1, m), o2 = __shfl_xor(b2, m);
                int   j1 = __shfl_xor(i1, m), j2 = __shfl_xor(i2, m);
                INSERT2(o1, j1);
                INSERT2(o2, j2);
            }
            if (lr == 0)
                ptop[wm + mi*16 + lg*4 + r][w & 1] = make_float2((float)i1, (float)i2);
        }
    __syncthreads();
    if (tid < 128){
        float2 h0 = ptop[tid][0], h1 = ptop[tid][1];
        partials[(size_t)(m0 + tid)*4 + blockIdx.y] =
            make_float4(h0.x, h0.y, h1.x, h1.y);
    }
}

// ---------------------------------------------------------------------------
// Exact f32 rescore of 16 candidates/row -> tokens; fused commitment loss.
// One wave per row, 16 rows per wave; grid 2048 x 256.
// ---------------------------------------------------------------------------
__global__ __launch_bounds__(256) void rescore_kernel(
    const float* __restrict__ Z, const float* __restrict__ CB,
    const float* __restrict__ cn, const float4* __restrict__ partials,
    float* __restrict__ tokf, float* __restrict__ loss)
{
    const int lane = threadIdx.x & 63;
    const int wv   = threadIdx.x >> 6;
    const int wgid = blockIdx.x*4 + wv;
    float csum = 0.0f;

    for (int rr=0; rr<16; ++rr){
        const int row = wgid*16 + rr;
        float4 z4 = *(const float4*)(Z + (size_t)row*256 + lane*4);
        int idx[16];
        #pragma unroll
        for (int pb=0; pb<4; ++pb){
            float4 p = partials[(size_t)row*4 + pb];
            idx[pb*4+0]=(int)p.x; idx[pb*4+1]=(int)p.y;
            idx[pb*4+2]=(int)p.z; idx[pb*4+3]=(int)p.w;
        }
        float best = FLT_MAX; int bi = INT_MAX;
        #pragma unroll
        for (int c=0;c<16;++c){
            int g = idx[c];
            float4 c4 = *(const float4*)(CB + (size_t)g*256 + lane*4);
            float p = z4.x*c4.x;
            p = fmaf(z4.y, c4.y, p);
            p = fmaf(z4.z, c4.z, p);
            p = fmaf(z4.w, c4.w, p);
            #pragma unroll
            for (int m=1;m<64;m<<=1) p += __shfl_xor(p, m);
            float d = cn[g] - 2.0f*p;
            if (d < best || (d == best && g < bi)){ best = d; bi = g; }
        }
        float4 c4 = *(const float4*)(CB + (size_t)bi*256 + lane*4);
        float dx=z4.x-c4.x, dy=z4.y-c4.y, dz=z4.z-c4.z, dw=z4.w-c4.w;
        float s = dx*dx + dy*dy + dz*dz + dw*dw;
        #pragma unroll
        for (int m=1;m<64;m<<=1) s += __shfl_xor(s, m);
        if (lane == 0){
            tokf[row] = (float)bi;
            csum += s;
        }
    }
    __shared__ float wsum[4];
    if (lane == 0) wsum[wv] = csum;
    __syncthreads();
    if (threadIdx.x == 0)
        atomicAdd(loss + 1, wsum[0]+wsum[1]+wsum[2]+wsum[3]);
}

// ---------------------------------------------------------------------------
// weight f32 -> bf16 conversion (dec_w1, dec_w2)
// ---------------------------------------------------------------------------
__global__ __launch_bounds__(256) void convw_kernel(
    const float* __restrict__ w1, const float* __restrict__ w2,
    ushort* __restrict__ o1, ushort* __restrict__ o2)
{
    const int i = (blockIdx.x*256 + threadIdx.x)*4;
    float4 a = *(const float4*)(w1 + i);
    ushort4 u; u.x=f2bf(a.x); u.y=f2bf(a.y); u.z=f2bf(a.z); u.w=f2bf(a.w);
    *(ushort4*)(o1 + i) = u;
    float4 b = *(const float4*)(w2 + i);
    ushort4 v; v.x=f2bf(b.x); v.y=f2bf(b.y); v.z=f2bf(b.z); v.w=f2bf(b.w);
    *(ushort4*)(o2 + i) = v;
}

// ---------------------------------------------------------------------------
// bf16 MFMA GEMM: Y[M,256] = gelu(A @ W^T + b), 128x128 tile, 4 waves.
// LOADER: 0 = plain bf16 A, 1 = gather bf16 codebook rows via tokens.
// ---------------------------------------------------------------------------
template<int LOADER>
__global__ __launch_bounds__(256) void mfma_gemm(
    const ushort* __restrict__ Abf,
    const ushort* __restrict__ cbb,
    const float* __restrict__ tokf,
    const ushort* __restrict__ Wbf,
    const float* __restrict__ bias,
    ushort* __restrict__ Ybf)
{
    __shared__ __align__(16) ushort Al[128][40];
    __shared__ __align__(16) ushort Wl[128][40];

    const int tid = threadIdx.x;
    const int m0 = blockIdx.x * 128;
    const int n0 = blockIdx.y * 128;
    const int srow = tid >> 1, shalf = (tid & 1) * 16;
    const int lane = tid & 63;
    const int w = tid >> 6;
    const int wm = (w >> 1) * 64, wn = (w & 1) * 64;
    const int lr = lane & 15, lg = lane >> 4;

    const ushort* asrc;
    if constexpr (LOADER == 1){
        int g = (int)tokf[m0 + srow];
        asrc = cbb + (size_t)g*256 + shalf;
    } else {
        asrc = Abf + (size_t)(m0 + srow)*256 + shalf;
    }
    const ushort* wsrc = Wbf + (size_t)(n0 + srow)*256 + shalf;

    f32x4 acc[4][4];
    #pragma unroll
    for (int mi=0;mi<4;++mi)
        #pragma unroll
        for (int ni=0;ni<4;++ni)
            acc[mi][ni] = (f32x4){0.f,0.f,0.f,0.f};

    for (int k0=0; k0<256; k0+=32){
        *(uint4*)&Al[srow][shalf]   = *(const uint4*)(asrc + k0);
        *(uint4*)&Al[srow][shalf+8] = *(const uint4*)(asrc + k0 + 8);
        *(uint4*)&Wl[srow][shalf]   = *(const uint4*)(wsrc + k0);
        *(uint4*)&Wl[srow][shalf+8] = *(const uint4*)(wsrc + k0 + 8);
        __syncthreads();

        short8 af[4], bfr[4];
        #pragma unroll
        for (int mi=0;mi<4;++mi)
            af[mi] = *(const short8*)&Al[wm + mi*16 + lr][lg*8];
        #pragma unroll
        for (int ni=0;ni<4;++ni)
            bfr[ni] = *(const short8*)&Wl[wn + ni*16 + lr][lg*8];
        #pragma unroll
        for (int mi=0;mi<4;++mi)
            #pragma unroll
            for (int ni=0;ni<4;++ni)
                acc[mi][ni] = __builtin_amdgcn_mfma_f32_16x16x32_bf16(
                    af[mi], bfr[ni], acc[mi][ni], 0, 0, 0);
        __syncthreads();
    }

    float bn[4];
    #pragma unroll
    for (int ni=0;ni<4;++ni) bn[ni] = bias[n0 + wn + ni*16 + lr];
    #pragma unroll
    for (int mi=0;mi<4;++mi)
        #pragma unroll
        for (int ni=0;ni<4;++ni)
            #pragma unroll
            for (int r=0;r<4;++r){
                int row = m0 + wm + mi*16 + lg*4 + r;
                float v = acc[mi][ni][r] + bn[ni];
                v = gelu_f(v);
                Ybf[(size_t)row*256 + n0 + wn + ni*16 + lr] = f2bf(v);
            }
}

// ---------------------------------------------------------------------------
// dec3: Y[T,48] = A_bf16 @ W3^T + b3 (f32 math), fused un-patchify + loss.
// ---------------------------------------------------------------------------
__global__ __launch_bounds__(192) void dec3_kernel(
    const ushort* __restrict__ Ain, const float* __restrict__ W,
    const float* __restrict__ bias, const float* __restrict__ frames,
    float* __restrict__ recon, float* __restrict__ loss)
{
    constexpr int BM=128, BK=16, K=256;
    __shared__ __align__(16) float As[BK][BM+4];
    __shared__ __align__(16) float Ws[BK][48+4];

    const int tid = threadIdx.x;
    const int tx = tid % 12, ty = tid / 12;
    const int m0 = blockIdx.x * BM;

    float acc[8][4];
    #pragma unroll
    for (int i=0;i<8;++i)
        #pragma unroll
        for (int j=0;j<4;++j) acc[i][j] = 0.0f;

    const int wq = tid & 3, wr = tid >> 2;
    const float* wp = W + (size_t)wr * K;

    for (int k0=0; k0<K; k0+=BK){
        for (int l=tid; l<512; l+=192){
            int r = l >> 2, qq = l & 3;
            ushort4 v = *(const ushort4*)(Ain + (size_t)(m0+r)*K + k0 + qq*4);
            As[qq*4+0][r]=bf2f(v.x); As[qq*4+1][r]=bf2f(v.y);
            As[qq*4+2][r]=bf2f(v.z); As[qq*4+3][r]=bf2f(v.w);
        }
        if (tid < 192){
            float4 v = *(const float4*)(wp + k0 + wq*4);
            Ws[wq*4+0][wr]=v.x; Ws[wq*4+1][wr]=v.y; Ws[wq*4+2][wr]=v.z; Ws[wq*4+3][wr]=v.w;
        }
        __syncthreads();
        #pragma unroll
        for (int kk=0; kk<BK; ++kk){
            float a[8], b[4];
            *(float4*)&a[0] = *(const float4*)&As[kk][ty*8];
            *(float4*)&a[4] = *(const float4*)&As[kk][ty*8+4];
            *(float4*)&b[0] = *(const float4*)&Ws[kk][tx*4];
            #pragma unroll
            for (int i=0;i<8;++i)
                #pragma unroll
                for (int j=0;j<4;++j)
                    acc[i][j] = fmaf(a[i], b[j], acc[i][j]);
        }
        __syncthreads();
    }

    const int cbase = tx*4;
    const int ph = cbase/12, rem = cbase - ph*12;
    float4 bv = *(const float4*)(bias + cbase);
    const float sc = 2.0f/255.0f;
    float ls = 0.0f;

    #pragma unroll
    for (int i=0;i<8;++i){
        int p = m0 + ty*8 + i;
        int b = p >> 12, nl = p & 4095, hh = nl >> 6, ww = nl & 63;
        size_t addr = (size_t)(((b*256 + hh*4 + ph)*256 + ww*4)*3 + rem);
        float4 y;
        y.x = acc[i][0] + bv.x; y.y = acc[i][1] + bv.y;
        y.z = acc[i][2] + bv.z; y.w = acc[i][3] + bv.w;
        float4 f = *(const float4*)(frames + addr);
        float t0 = f.x*sc-1.0f, t1 = f.y*sc-1.0f, t2 = f.z*sc-1.0f, t3 = f.w*sc-1.0f;
        float d0 = y.x-t0, d1 = y.y-t1, d2 = y.z-t2, d3 = y.w-t3;
        ls += d0*d0 + d1*d1 + d2*d2 + d3*d3;
        *(float4*)(recon + addr) = y;
    }

    #pragma unroll
    for (int off=32; off>0; off>>=1) ls += __shfl_down(ls, off);
    __shared__ float wsum[3];
    int lane = tid & 63, wv = tid >> 6;
    if (lane == 0) wsum[wv] = ls;
    __syncthreads();
    if (tid == 0) atomicAdd(loss + 0, wsum[0]+wsum[1]+wsum[2]);
}

__global__ void finalize_kernel(float* __restrict__ loss){
    if (threadIdx.x == 0 && blockIdx.x == 0){
        loss[0] = loss[0] * (1.0f/6291456.0f);
        float c = loss[1] * (1.0f/33554432.0f);
        loss[1] = c;
        loss[2] = c;
    }
}

extern "C" void kernel_launch(void* const* d_in, const int* in_sizes, int n_in,
                              void* d_out, int out_size, void* d_ws, size_t ws_size,
                              hipStream_t stream)
{
    (void)in_sizes; (void)n_in; (void)out_size; (void)ws_size;
    const float* frames   = (const float*)d_in[0];
    const float* enc_w1   = (const float*)d_in[1];
    const float* enc_b1   = (const float*)d_in[2];
    const float* enc_w2   = (const float*)d_in[3];
    const float* enc_b2   = (const float*)d_in[4];
    const float* enc_w3   = (const float*)d_in[5];
    const float* enc_b3   = (const float*)d_in[6];
    const float* codebook = (const float*)d_in[7];
    const float* dec_w1   = (const float*)d_in[8];
    const float* dec_b1   = (const float*)d_in[9];
    const float* dec_w2   = (const float*)d_in[10];
    const float* dec_b2   = (const float*)d_in[11];
    const float* dec_w3   = (const float*)d_in[12];
    const float* dec_b3   = (const float*)d_in[13];

    float*  A    = (float*)d_ws;                       // [T,256] f32 (z_e)
    float*  Bws  = A + (size_t)T_ROWS * 256;           // [T,256] f32 region
    // time-disjoint sub-allocations of the Bws region:
    ushort* Zb       = (ushort*)Bws;                   // [T,256] bf16 (<=16.7M floats)
    ushort* Y1       = (ushort*)Bws;                   // dec1 out (after rescore)
    float4* partials = (float4*)(Bws + 17000000);      // 131072*4 float4 (2.1M floats)
    float*  smalls   = Bws + 20971520;
    float*  cn       = smalls;                         // 512
    ushort* cbb      = (ushort*)(smalls + 512);        // 131072 ushorts
    ushort* w1b      = (ushort*)(smalls + 66048);      // 65536 ushorts
    ushort* w2b      = (ushort*)(smalls + 98816);      // 65536 ushorts
    ushort* Y2       = (ushort*)A;                     // dec2 out (A dead after rescore)

    float* recon = (float*)d_out;                      // 6,291,456
    float* tokf  = recon + 6291456;                    // 131,072
    float* loss  = tokf + 131072;                      // 3 scalars

    hipMemsetAsync(loss, 0, 3*sizeof(float), stream);

    dim3 blk(256), grid2(T_ROWS/128, 2);
    // encoder (f32 — token path needs f32-level z_e)
    gemm_kernel<48,  true, 1><<<grid2, blk, 0, stream>>>(nullptr, frames, enc_w1, enc_b1, A);
    gemm_kernel<256, true, 0><<<grid2, blk, 0, stream>>>(A, nullptr, enc_w2, enc_b2, Bws);
    gemm_kernel<256, false,0><<<grid2, blk, 0, stream>>>(Bws, nullptr, enc_w3, enc_b3, A);
    // vector quantization: bf16 approx + f32 rescore
    zconv_kernel<<<dim3(16384), blk, 0, stream>>>(A, Zb);
    cnorm_kernel<<<dim3(128), blk, 0, stream>>>(codebook, cn, cbb);
    tokens_mfma<<<dim3(T_ROWS/128, 4), blk, 0, stream>>>(Zb, cbb, cn, partials);
    rescore_kernel<<<dim3(2048), blk, 0, stream>>>(A, codebook, cn, partials, tokf, loss);
    // decoder (bf16 MFMA)
    convw_kernel<<<dim3(64), blk, 0, stream>>>(dec_w1, dec_w2, w1b, w2b);
    mfma_gemm<1><<<grid2, blk, 0, stream>>>(nullptr, cbb, tokf, w1b, dec_b1, Y1);
    mfma_gemm<0><<<grid2, blk, 0, stream>>>(Y1, nullptr, nullptr, w2b, dec_b2, Y2);
    dec3_kernel<<<dim3(T_ROWS/128), dim3(192), 0, stream>>>(Y2, dec_w3, dec_b3, frames, recon, loss);
    finalize_kernel<<<dim3(1), dim3(64), 0, stream>>>(loss);
}

// Round 4
// 847.126 us; speedup vs baseline: 2.1004x; 1.2151x over previous
//
#include <hip/hip_runtime.h>
#include <hip/hip_bf16.h>
#include <math.h>
#include <float.h>
#include <limits.h>

#define T_ROWS 131072   // 32 * 4096 patches

typedef __attribute__((ext_vector_type(8))) short short8;
typedef __attribute__((ext_vector_type(4))) float f32x4;

__device__ __forceinline__ float gelu_f(float x){
    return 0.5f * x * (1.0f + erff(x * 0.7071067811865475f));
}
__device__ __forceinline__ float bf2f(ushort u){
    union { unsigned int i; float f; } v; v.i = ((unsigned int)u) << 16; return v.f;
}
__device__ __forceinline__ ushort f2bf(float f){
    union { float f; unsigned int i; } v; v.f = f;
    unsigned int i = v.i;
    unsigned int r = (i + 0x7fffu + ((i >> 16) & 1u)) >> 16;
    return (ushort)r;
}
// exact 3-way truncation split: x ~= b0+b1+b2 (each bf16), >=24 mantissa bits
__device__ __forceinline__ void split3(float x, ushort &u0, ushort &u1, ushort &u2){
    union { float f; unsigned int i; } v; v.f = x;
    u0 = (ushort)(v.i >> 16);
    union { unsigned int i; float f; } h0; h0.i = ((unsigned int)u0) << 16;
    float r = x - h0.f;                       // exact (Sterbenz)
    union { float f; unsigned int i; } vr; vr.f = r;
    u1 = (ushort)(vr.i >> 16);
    union { unsigned int i; float f; } h1; h1.i = ((unsigned int)u1) << 16;
    float r2 = r - h1.f;                      // exact
    union { float f; unsigned int i; } v2; v2.f = r2;
    u2 = (ushort)(v2.i >> 16);
}

// ---------------------------------------------------------------------------
// f32 tiled GEMM (enc1 only): C[M,256] = gelu(patchify(frames) @ W^T + b)
// ---------------------------------------------------------------------------
template<int K, bool GELU, int LOADER>
__global__ __launch_bounds__(256) void gemm_kernel(
    const float* __restrict__ Ain,
    const float* __restrict__ frames,
    const float* __restrict__ W,
    const float* __restrict__ bias,
    float* __restrict__ Cout)
{
    constexpr int BM=128, BN=128, BK=16;
    __shared__ __align__(16) float As[BK][BM+4];
    __shared__ __align__(16) float Ws[BK][BN+4];

    const int tid = threadIdx.x;
    const int tx = tid & 15, ty = tid >> 4;
    const int m0 = blockIdx.x * BM;
    const int c0 = blockIdx.y * BN;

    const int q  = tid & 3;
    const int r0 = tid >> 2;

    const float* aptr0 = nullptr;
    const float* aptr1 = nullptr;
    int base0 = 0, base1 = 0;
    if constexpr (LOADER == 0){
        aptr0 = Ain + (size_t)(m0 + r0) * K;
        aptr1 = aptr0 + (size_t)64 * K;
    } else {
        int p0 = m0 + r0;
        int b = p0 >> 12, nl = p0 & 4095, hh = nl >> 6, ww = nl & 63;
        base0 = ((b*256 + hh*4)*256 + ww*4)*3;
        int p1 = p0 + 64;
        b = p1 >> 12; nl = p1 & 4095; hh = nl >> 6; ww = nl & 63;
        base1 = ((b*256 + hh*4)*256 + ww*4)*3;
    }
    const float* wptr0 = W + (size_t)(c0 + r0) * K;
    const float* wptr1 = wptr0 + (size_t)64 * K;

    float acc[8][8];
    #pragma unroll
    for (int i=0;i<8;++i)
        #pragma unroll
        for (int j=0;j<8;++j) acc[i][j] = 0.0f;

    for (int k0 = 0; k0 < K; k0 += BK){
        const int k = k0 + q*4;
        float4 va, vb;
        if constexpr (LOADER == 1){
            const int ph = k / 12, rem = k - ph*12;
            va = *(const float4*)(frames + base0 + ph*768 + rem);
            vb = *(const float4*)(frames + base1 + ph*768 + rem);
            const float sc = 2.0f/255.0f;
            va.x = va.x*sc - 1.0f; va.y = va.y*sc - 1.0f;
            va.z = va.z*sc - 1.0f; va.w = va.w*sc - 1.0f;
            vb.x = vb.x*sc - 1.0f; vb.y = vb.y*sc - 1.0f;
            vb.z = vb.z*sc - 1.0f; vb.w = vb.w*sc - 1.0f;
        } else {
            va = *(const float4*)(aptr0 + k);
            vb = *(const float4*)(aptr1 + k);
        }
        As[q*4+0][r0]    = va.x; As[q*4+1][r0]    = va.y;
        As[q*4+2][r0]    = va.z; As[q*4+3][r0]    = va.w;
        As[q*4+0][r0+64] = vb.x; As[q*4+1][r0+64] = vb.y;
        As[q*4+2][r0+64] = vb.z; As[q*4+3][r0+64] = vb.w;

        float4 wa = *(const float4*)(wptr0 + k);
        float4 wb = *(const float4*)(wptr1 + k);
        Ws[q*4+0][r0]    = wa.x; Ws[q*4+1][r0]    = wa.y;
        Ws[q*4+2][r0]    = wa.z; Ws[q*4+3][r0]    = wa.w;
        Ws[q*4+0][r0+64] = wb.x; Ws[q*4+1][r0+64] = wb.y;
        Ws[q*4+2][r0+64] = wb.z; Ws[q*4+3][r0+64] = wb.w;

        __syncthreads();
        #pragma unroll
        for (int kk=0; kk<BK; ++kk){
            float a[8], b[8];
            *(float4*)&a[0] = *(const float4*)&As[kk][ty*4];
            *(float4*)&a[4] = *(const float4*)&As[kk][64+ty*4];
            *(float4*)&b[0] = *(const float4*)&Ws[kk][tx*4];
            *(float4*)&b[4] = *(const float4*)&Ws[kk][64+tx*4];
            #pragma unroll
            for (int i=0;i<8;++i)
                #pragma unroll
                for (int j=0;j<8;++j)
                    acc[i][j] = fmaf(a[i], b[j], acc[i][j]);
        }
        __syncthreads();
    }

    float bj[8];
    *(float4*)&bj[0] = *(const float4*)(bias + c0 + tx*4);
    *(float4*)&bj[4] = *(const float4*)(bias + c0 + 64 + tx*4);
    #pragma unroll
    for (int i=0;i<8;++i){
        const int row = m0 + ((i<4) ? (ty*4+i) : (64+ty*4+i-4));
        float o[8];
        #pragma unroll
        for (int j=0;j<8;++j){
            float x = acc[i][j] + bj[j];
            o[j] = GELU ? gelu_f(x) : x;
        }
        float* dst = Cout + (size_t)row*256 + c0 + tx*4;
        *(float4*)dst      = *(const float4*)&o[0];
        *(float4*)(dst+64) = *(const float4*)&o[4];
    }
}

// ---------------------------------------------------------------------------
// weight prep: 3-way split enc_w2/enc_w3; bf16 round dec_w1/dec_w2
// ---------------------------------------------------------------------------
__global__ __launch_bounds__(256) void wsplit_kernel(
    const float* __restrict__ w2, const float* __restrict__ w3,
    const float* __restrict__ d1, const float* __restrict__ d2,
    ushort* __restrict__ w2s0, ushort* __restrict__ w2s1, ushort* __restrict__ w2s2,
    ushort* __restrict__ w3s0, ushort* __restrict__ w3s1, ushort* __restrict__ w3s2,
    ushort* __restrict__ w1b, ushort* __restrict__ w2b)
{
    const int i = (blockIdx.x*256 + threadIdx.x)*4;
    float4 a = *(const float4*)(w2 + i);
    ushort4 s0, s1, s2;
    split3(a.x, s0.x, s1.x, s2.x); split3(a.y, s0.y, s1.y, s2.y);
    split3(a.z, s0.z, s1.z, s2.z); split3(a.w, s0.w, s1.w, s2.w);
    *(ushort4*)(w2s0+i)=s0; *(ushort4*)(w2s1+i)=s1; *(ushort4*)(w2s2+i)=s2;
    float4 b = *(const float4*)(w3 + i);
    split3(b.x, s0.x, s1.x, s2.x); split3(b.y, s0.y, s1.y, s2.y);
    split3(b.z, s0.z, s1.z, s2.z); split3(b.w, s0.w, s1.w, s2.w);
    *(ushort4*)(w3s0+i)=s0; *(ushort4*)(w3s1+i)=s1; *(ushort4*)(w3s2+i)=s2;
    float4 c = *(const float4*)(d1 + i);
    ushort4 u; u.x=f2bf(c.x); u.y=f2bf(c.y); u.z=f2bf(c.z); u.w=f2bf(c.w);
    *(ushort4*)(w1b+i) = u;
    float4 d = *(const float4*)(d2 + i);
    u.x=f2bf(d.x); u.y=f2bf(d.y); u.z=f2bf(d.z); u.w=f2bf(d.w);
    *(ushort4*)(w2b+i) = u;
}

// ---------------------------------------------------------------------------
// ||c||^2 per code (f32 exact) + bf16 codebook copy
// ---------------------------------------------------------------------------
__global__ __launch_bounds__(256) void cnorm_kernel(
    const float* __restrict__ cb, float* __restrict__ cn,
    ushort* __restrict__ cbb)
{
    const int lane = threadIdx.x & 63;
    const int code = blockIdx.x*4 + (threadIdx.x >> 6);
    float4 v = ((const float4*)(cb + (size_t)code*256))[lane];
    ushort4 u; u.x=f2bf(v.x); u.y=f2bf(v.y); u.z=f2bf(v.z); u.w=f2bf(v.w);
    *(ushort4*)(cbb + (size_t)code*256 + lane*4) = u;
    float s = v.x*v.x + v.y*v.y + v.z*v.z + v.w*v.w;
    #pragma unroll
    for (int m=1; m<64; m<<=1) s += __shfl_xor(s, m);
    if (lane == 0) cn[code] = s;
}

// ---------------------------------------------------------------------------
// f32-faithful MFMA GEMM via 6-term split-bf16:
// C[M,256] = act(A[M,256] @ W[256,256]^T + b), A split in-kernel, W pre-split.
// 128x128 tile, 4 waves (2x2 of 64x64), 16x16x32 MFMA, BK=32.
// ---------------------------------------------------------------------------
template<bool GELU>
__global__ __launch_bounds__(256) void split6_gemm(
    const float* __restrict__ Ain,
    const ushort* __restrict__ W0, const ushort* __restrict__ W1,
    const ushort* __restrict__ W2,
    const float* __restrict__ bias,
    float* __restrict__ Cout)
{
    __shared__ __align__(16) ushort Al[3][128][40];
    __shared__ __align__(16) ushort Wl[3][128][40];

    const int tid = threadIdx.x;
    const int m0 = blockIdx.x * 128;
    const int n0 = blockIdx.y * 128;
    const int srow = tid >> 1, shalf = (tid & 1) * 16;
    const int lane = tid & 63;
    const int w = tid >> 6;
    const int wm = (w >> 1) * 64, wn = (w & 1) * 64;
    const int lr = lane & 15, lg = lane >> 4;

    const float*  asrc = Ain + (size_t)(m0 + srow)*256 + shalf;
    const ushort* ws0  = W0  + (size_t)(n0 + srow)*256 + shalf;
    const ushort* ws1  = W1  + (size_t)(n0 + srow)*256 + shalf;
    const ushort* ws2  = W2  + (size_t)(n0 + srow)*256 + shalf;

    f32x4 acc[4][4];
    #pragma unroll
    for (int mi=0;mi<4;++mi)
        #pragma unroll
        for (int ni=0;ni<4;++ni)
            acc[mi][ni] = (f32x4){0.f,0.f,0.f,0.f};

    for (int k0=0; k0<256; k0+=32){
        float x[16];
        *(float4*)&x[0]  = *(const float4*)(asrc + k0);
        *(float4*)&x[4]  = *(const float4*)(asrc + k0 + 4);
        *(float4*)&x[8]  = *(const float4*)(asrc + k0 + 8);
        *(float4*)&x[12] = *(const float4*)(asrc + k0 + 12);
        ushort t0[16], t1[16], t2[16];
        #pragma unroll
        for (int e=0;e<16;++e) split3(x[e], t0[e], t1[e], t2[e]);
        *(uint4*)&Al[0][srow][shalf]   = *(const uint4*)&t0[0];
        *(uint4*)&Al[0][srow][shalf+8] = *(const uint4*)&t0[8];
        *(uint4*)&Al[1][srow][shalf]   = *(const uint4*)&t1[0];
        *(uint4*)&Al[1][srow][shalf+8] = *(const uint4*)&t1[8];
        *(uint4*)&Al[2][srow][shalf]   = *(const uint4*)&t2[0];
        *(uint4*)&Al[2][srow][shalf+8] = *(const uint4*)&t2[8];
        *(uint4*)&Wl[0][srow][shalf]   = *(const uint4*)(ws0 + k0);
        *(uint4*)&Wl[0][srow][shalf+8] = *(const uint4*)(ws0 + k0 + 8);
        *(uint4*)&Wl[1][srow][shalf]   = *(const uint4*)(ws1 + k0);
        *(uint4*)&Wl[1][srow][shalf+8] = *(const uint4*)(ws1 + k0 + 8);
        *(uint4*)&Wl[2][srow][shalf]   = *(const uint4*)(ws2 + k0);
        *(uint4*)&Wl[2][srow][shalf+8] = *(const uint4*)(ws2 + k0 + 8);
        __syncthreads();

        short8 b0[4], b1[4], b2[4];
        #pragma unroll
        for (int ni=0;ni<4;++ni){
            b0[ni] = *(const short8*)&Wl[0][wn + ni*16 + lr][lg*8];
            b1[ni] = *(const short8*)&Wl[1][wn + ni*16 + lr][lg*8];
            b2[ni] = *(const short8*)&Wl[2][wn + ni*16 + lr][lg*8];
        }
        #pragma unroll
        for (int mi=0;mi<4;++mi){
            short8 a0 = *(const short8*)&Al[0][wm + mi*16 + lr][lg*8];
            short8 a1 = *(const short8*)&Al[1][wm + mi*16 + lr][lg*8];
            short8 a2 = *(const short8*)&Al[2][wm + mi*16 + lr][lg*8];
            #pragma unroll
            for (int ni=0;ni<4;++ni)
                acc[mi][ni] = __builtin_amdgcn_mfma_f32_16x16x32_bf16(a0, b0[ni], acc[mi][ni], 0,0,0);
            #pragma unroll
            for (int ni=0;ni<4;++ni)
                acc[mi][ni] = __builtin_amdgcn_mfma_f32_16x16x32_bf16(a0, b1[ni], acc[mi][ni], 0,0,0);
            #pragma unroll
            for (int ni=0;ni<4;++ni)
                acc[mi][ni] = __builtin_amdgcn_mfma_f32_16x16x32_bf16(a1, b0[ni], acc[mi][ni], 0,0,0);
            #pragma unroll
            for (int ni=0;ni<4;++ni)
                acc[mi][ni] = __builtin_amdgcn_mfma_f32_16x16x32_bf16(a0, b2[ni], acc[mi][ni], 0,0,0);
            #pragma unroll
            for (int ni=0;ni<4;++ni)
                acc[mi][ni] = __builtin_amdgcn_mfma_f32_16x16x32_bf16(a1, b1[ni], acc[mi][ni], 0,0,0);
            #pragma unroll
            for (int ni=0;ni<4;++ni)
                acc[mi][ni] = __builtin_amdgcn_mfma_f32_16x16x32_bf16(a2, b0[ni], acc[mi][ni], 0,0,0);
        }
        __syncthreads();
    }

    float bn[4];
    #pragma unroll
    for (int ni=0;ni<4;++ni) bn[ni] = bias[n0 + wn + ni*16 + lr];
    #pragma unroll
    for (int mi=0;mi<4;++mi)
        #pragma unroll
        for (int ni=0;ni<4;++ni)
            #pragma unroll
            for (int r=0;r<4;++r){
                int row = m0 + wm + mi*16 + lg*4 + r;
                float v = acc[mi][ni][r] + bn[ni];
                if (GELU) v = gelu_f(v);
                Cout[(size_t)row*256 + n0 + wn + ni*16 + lr] = v;
            }
}

#define INSERT2(dv, iv) do { \
    float _d = (dv); int _i = (iv); \
    if (_d < b1 || (_d == b1 && _i < i1)){ b2=b1; i2=i1; b1=_d; i1=_i; } \
    else if (_d < b2 || (_d == b2 && _i < i2)){ b2=_d; i2=_i; } \
} while(0)

// ---------------------------------------------------------------------------
// Approximate distance pass (bf16 MFMA), f32 z_e converted in-kernel.
// Per block: 128 rows x 128 codes; writes 4 candidate indices per colblock.
// ---------------------------------------------------------------------------
__global__ __launch_bounds__(256) void tokens_mfma(
    const float* __restrict__ Zf, const ushort* __restrict__ CBb,
    const float* __restrict__ cn, float4* __restrict__ partials)
{
    __shared__ __align__(16) ushort Al[128][40];
    __shared__ __align__(16) ushort Wl[128][40];
    __shared__ float2 ptop[128][2];

    const int tid = threadIdx.x;
    const int m0 = blockIdx.x * 128;
    const int n0 = blockIdx.y * 128;
    const int srow = tid >> 1, shalf = (tid & 1) * 16;
    const int lane = tid & 63;
    const int w = tid >> 6;
    const int wm = (w >> 1) * 64, wn = (w & 1) * 64;
    const int lr = lane & 15, lg = lane >> 4;

    const float*  asrc = Zf  + (size_t)(m0 + srow)*256 + shalf;
    const ushort* wsrc = CBb + (size_t)(n0 + srow)*256 + shalf;

    f32x4 acc[4][4];
    #pragma unroll
    for (int mi=0;mi<4;++mi)
        #pragma unroll
        for (int ni=0;ni<4;++ni)
            acc[mi][ni] = (f32x4){0.f,0.f,0.f,0.f};

    for (int k0=0; k0<256; k0+=32){
        float4 f0 = *(const float4*)(asrc + k0);
        float4 f1 = *(const float4*)(asrc + k0 + 4);
        float4 f2 = *(const float4*)(asrc + k0 + 8);
        float4 f3 = *(const float4*)(asrc + k0 + 12);
        ushort t[16];
        t[0]=f2bf(f0.x); t[1]=f2bf(f0.y); t[2]=f2bf(f0.z); t[3]=f2bf(f0.w);
        t[4]=f2bf(f1.x); t[5]=f2bf(f1.y); t[6]=f2bf(f1.z); t[7]=f2bf(f1.w);
        t[8]=f2bf(f2.x); t[9]=f2bf(f2.y); t[10]=f2bf(f2.z); t[11]=f2bf(f2.w);
        t[12]=f2bf(f3.x); t[13]=f2bf(f3.y); t[14]=f2bf(f3.z); t[15]=f2bf(f3.w);
        *(uint4*)&Al[srow][shalf]   = *(const uint4*)&t[0];
        *(uint4*)&Al[srow][shalf+8] = *(const uint4*)&t[8];
        *(uint4*)&Wl[srow][shalf]   = *(const uint4*)(wsrc + k0);
        *(uint4*)&Wl[srow][shalf+8] = *(const uint4*)(wsrc + k0 + 8);
        __syncthreads();

        short8 af[4], bfr[4];
        #pragma unroll
        for (int mi=0;mi<4;++mi)
            af[mi] = *(const short8*)&Al[wm + mi*16 + lr][lg*8];
        #pragma unroll
        for (int ni=0;ni<4;++ni)
            bfr[ni] = *(const short8*)&Wl[wn + ni*16 + lr][lg*8];
        #pragma unroll
        for (int mi=0;mi<4;++mi)
            #pragma unroll
            for (int ni=0;ni<4;++ni)
                acc[mi][ni] = __builtin_amdgcn_mfma_f32_16x16x32_bf16(
                    af[mi], bfr[ni], acc[mi][ni], 0, 0, 0);
        __syncthreads();
    }

    float cnl[4];
    #pragma unroll
    for (int ni=0;ni<4;++ni) cnl[ni] = cn[n0 + wn + ni*16 + lr];

    #pragma unroll
    for (int mi=0;mi<4;++mi)
        #pragma unroll
        for (int r=0;r<4;++r){
            float b1 = FLT_MAX, b2 = FLT_MAX;
            int   i1 = INT_MAX, i2 = INT_MAX;
            #pragma unroll
            for (int ni=0;ni<4;++ni){
                float d = cnl[ni] - 2.0f*acc[mi][ni][r];
                int col = n0 + wn + ni*16 + lr;
                INSERT2(d, col);
            }
            #pragma unroll
            for (int m=1; m<16; m<<=1){
                float o1 = __shfl_xor(b1, m), o2 = __shfl_xor(b2, m);
                int   j1 = __shfl_xor(i1, m), j2 = __shfl_xor(i2, m);
                INSERT2(o1, j1);
                INSERT2(o2, j2);
            }
            if (lr == 0)
                ptop[wm + mi*16 + lg*4 + r][w & 1] = make_float2((float)i1, (float)i2);
        }
    __syncthreads();
    if (tid < 128){
        float2 h0 = ptop[tid][0], h1 = ptop[tid][1];
        partials[(size_t)(m0 + tid)*4 + blockIdx.y] =
            make_float4(h0.x, h0.y, h1.x, h1.y);
    }
}

// ---------------------------------------------------------------------------
// Exact f32 rescore of 16 candidates/row -> tokens; fused commitment loss.
// ---------------------------------------------------------------------------
__global__ __launch_bounds__(256) void rescore_kernel(
    const float* __restrict__ Z, const float* __restrict__ CB,
    const float* __restrict__ cn, const float4* __restrict__ partials,
    float* __restrict__ tokf, float* __restrict__ loss)
{
    const int lane = threadIdx.x & 63;
    const int wv   = threadIdx.x >> 6;
    const int wgid = blockIdx.x*4 + wv;
    float csum = 0.0f;

    for (int rr=0; rr<16; ++rr){
        const int row = wgid*16 + rr;
        float4 z4 = *(const float4*)(Z + (size_t)row*256 + lane*4);
        int idx[16];
        #pragma unroll
        for (int pb=0; pb<4; ++pb){
            float4 p = partials[(size_t)row*4 + pb];
            idx[pb*4+0]=(int)p.x; idx[pb*4+1]=(int)p.y;
            idx[pb*4+2]=(int)p.z; idx[pb*4+3]=(int)p.w;
        }
        float best = FLT_MAX; int bi = INT_MAX;
        #pragma unroll
        for (int c=0;c<16;++c){
            int g = idx[c];
            float4 c4 = *(const float4*)(CB + (size_t)g*256 + lane*4);
            float p = z4.x*c4.x;
            p = fmaf(z4.y, c4.y, p);
            p = fmaf(z4.z, c4.z, p);
            p = fmaf(z4.w, c4.w, p);
            #pragma unroll
            for (int m=1;m<64;m<<=1) p += __shfl_xor(p, m);
            float d = cn[g] - 2.0f*p;
            if (d < best || (d == best && g < bi)){ best = d; bi = g; }
        }
        float4 c4 = *(const float4*)(CB + (size_t)bi*256 + lane*4);
        float dx=z4.x-c4.x, dy=z4.y-c4.y, dz=z4.z-c4.z, dw=z4.w-c4.w;
        float s = dx*dx + dy*dy + dz*dz + dw*dw;
        #pragma unroll
        for (int m=1;m<64;m<<=1) s += __shfl_xor(s, m);
        if (lane == 0){
            tokf[row] = (float)bi;
            csum += s;
        }
    }
    __shared__ float wsum[4];
    if (lane == 0) wsum[wv] = csum;
    __syncthreads();
    if (threadIdx.x == 0)
        atomicAdd(loss + 1, wsum[0]+wsum[1]+wsum[2]+wsum[3]);
}

// ---------------------------------------------------------------------------
// bf16 MFMA GEMM (decoder 1/2): Y[M,256] = gelu(A @ W^T + b)
// LOADER: 0 = plain bf16 A, 1 = gather bf16 codebook rows via tokens.
// ---------------------------------------------------------------------------
template<int LOADER>
__global__ __launch_bounds__(256) void mfma_gemm(
    const ushort* __restrict__ Abf,
    const ushort* __restrict__ cbb,
    const float* __restrict__ tokf,
    const ushort* __restrict__ Wbf,
    const float* __restrict__ bias,
    ushort* __restrict__ Ybf)
{
    __shared__ __align__(16) ushort Al[128][40];
    __shared__ __align__(16) ushort Wl[128][40];

    const int tid = threadIdx.x;
    const int m0 = blockIdx.x * 128;
    const int n0 = blockIdx.y * 128;
    const int srow = tid >> 1, shalf = (tid & 1) * 16;
    const int lane = tid & 63;
    const int w = tid >> 6;
    const int wm = (w >> 1) * 64, wn = (w & 1) * 64;
    const int lr = lane & 15, lg = lane >> 4;

    const ushort* asrc;
    if constexpr (LOADER == 1){
        int g = (int)tokf[m0 + srow];
        asrc = cbb + (size_t)g*256 + shalf;
    } else {
        asrc = Abf + (size_t)(m0 + srow)*256 + shalf;
    }
    const ushort* wsrc = Wbf + (size_t)(n0 + srow)*256 + shalf;

    f32x4 acc[4][4];
    #pragma unroll
    for (int mi=0;mi<4;++mi)
        #pragma unroll
        for (int ni=0;ni<4;++ni)
            acc[mi][ni] = (f32x4){0.f,0.f,0.f,0.f};

    for (int k0=0; k0<256; k0+=32){
        *(uint4*)&Al[srow][shalf]   = *(const uint4*)(asrc + k0);
        *(uint4*)&Al[srow][shalf+8] = *(const uint4*)(asrc + k0 + 8);
        *(uint4*)&Wl[srow][shalf]   = *(const uint4*)(wsrc + k0);
        *(uint4*)&Wl[srow][shalf+8] = *(const uint4*)(wsrc + k0 + 8);
        __syncthreads();

        short8 af[4], bfr[4];
        #pragma unroll
        for (int mi=0;mi<4;++mi)
            af[mi] = *(const short8*)&Al[wm + mi*16 + lr][lg*8];
        #pragma unroll
        for (int ni=0;ni<4;++ni)
            bfr[ni] = *(const short8*)&Wl[wn + ni*16 + lr][lg*8];
        #pragma unroll
        for (int mi=0;mi<4;++mi)
            #pragma unroll
            for (int ni=0;ni<4;++ni)
                acc[mi][ni] = __builtin_amdgcn_mfma_f32_16x16x32_bf16(
                    af[mi], bfr[ni], acc[mi][ni], 0, 0, 0);
        __syncthreads();
    }

    float bn[4];
    #pragma unroll
    for (int ni=0;ni<4;++ni) bn[ni] = bias[n0 + wn + ni*16 + lr];
    #pragma unroll
    for (int mi=0;mi<4;++mi)
        #pragma unroll
        for (int ni=0;ni<4;++ni)
            #pragma unroll
            for (int r=0;r<4;++r){
                int row = m0 + wm + mi*16 + lg*4 + r;
                float v = acc[mi][ni][r] + bn[ni];
                v = gelu_f(v);
                Ybf[(size_t)row*256 + n0 + wn + ni*16 + lr] = f2bf(v);
            }
}

// ---------------------------------------------------------------------------
// dec3 MFMA: Y[T,48] = A_bf16 @ W3^T + b3 (W3 converted in-kernel),
// fused un-patchify + recon loss. 256 rows/block, 4 waves of 64 rows.
// ---------------------------------------------------------------------------
__global__ __launch_bounds__(256) void dec3_mfma(
    const ushort* __restrict__ Ain, const float* __restrict__ W,
    const float* __restrict__ bias, const float* __restrict__ frames,
    float* __restrict__ recon, float* __restrict__ loss)
{
    __shared__ __align__(16) ushort Al[256][40];
    __shared__ __align__(16) ushort Wl[48][40];

    const int tid = threadIdx.x;
    const int m0 = blockIdx.x * 256;
    const int lane = tid & 63;
    const int w = tid >> 6;
    const int lr = lane & 15, lg = lane >> 4;

    const ushort* asrc = Ain + (size_t)(m0 + tid)*256;

    f32x4 acc[4][3];
    #pragma unroll
    for (int mi=0;mi<4;++mi)
        #pragma unroll
        for (int ni=0;ni<3;++ni)
            acc[mi][ni] = (f32x4){0.f,0.f,0.f,0.f};

    for (int k0=0; k0<256; k0+=32){
        *(uint4*)&Al[tid][0]  = *(const uint4*)(asrc + k0);
        *(uint4*)&Al[tid][8]  = *(const uint4*)(asrc + k0 + 8);
        *(uint4*)&Al[tid][16] = *(const uint4*)(asrc + k0 + 16);
        *(uint4*)&Al[tid][24] = *(const uint4*)(asrc + k0 + 24);
        if (tid < 96){
            const int wrow = tid >> 1, wh = (tid & 1)*16;
            const float* wp = W + (size_t)wrow*256 + k0 + wh;
            float4 f0 = *(const float4*)(wp);
            float4 f1 = *(const float4*)(wp+4);
            float4 f2 = *(const float4*)(wp+8);
            float4 f3 = *(const float4*)(wp+12);
            ushort t[16];
            t[0]=f2bf(f0.x); t[1]=f2bf(f0.y); t[2]=f2bf(f0.z); t[3]=f2bf(f0.w);
            t[4]=f2bf(f1.x); t[5]=f2bf(f1.y); t[6]=f2bf(f1.z); t[7]=f2bf(f1.w);
            t[8]=f2bf(f2.x); t[9]=f2bf(f2.y); t[10]=f2bf(f2.z); t[11]=f2bf(f2.w);
            t[12]=f2bf(f3.x); t[13]=f2bf(f3.y); t[14]=f2bf(f3.z); t[15]=f2bf(f3.w);
            *(uint4*)&Wl[wrow][wh]   = *(const uint4*)&t[0];
            *(uint4*)&Wl[wrow][wh+8] = *(const uint4*)&t[8];
        }
        __syncthreads();

        short8 bfr[3];
        #pragma unroll
        for (int ni=0;ni<3;++ni)
            bfr[ni] = *(const short8*)&Wl[ni*16 + lr][lg*8];
        #pragma unroll
        for (int mi=0;mi<4;++mi){
            short8 af = *(const short8*)&Al[w*64 + mi*16 + lr][lg*8];
            #pragma unroll
            for (int ni=0;ni<3;++ni)
                acc[mi][ni] = __builtin_amdgcn_mfma_f32_16x16x32_bf16(
                    af, bfr[ni], acc[mi][ni], 0, 0, 0);
        }
        __syncthreads();
    }

    float bn[3]; int phv[3], remv[3];
    #pragma unroll
    for (int ni=0;ni<3;++ni){
        int col = ni*16 + lr;
        bn[ni] = bias[col];
        phv[ni] = col / 12;
        remv[ni] = col - phv[ni]*12;
    }
    const float sc = 2.0f/255.0f;
    float ls = 0.0f;
    #pragma unroll
    for (int mi=0;mi<4;++mi)
        #pragma unroll
        for (int ni=0;ni<3;++ni)
            #pragma unroll
            for (int r=0;r<4;++r){
                int p = m0 + w*64 + mi*16 + lg*4 + r;
                int b = p >> 12, nl = p & 4095, hh = nl >> 6, ww = nl & 63;
                size_t addr = (size_t)(((b*256 + hh*4 + phv[ni])*256 + ww*4)*3 + remv[ni]);
                float y = acc[mi][ni][r] + bn[ni];
                float t = frames[addr]*sc - 1.0f;
                float d = y - t;
                ls += d*d;
                recon[addr] = y;
            }

    #pragma unroll
    for (int off=32; off>0; off>>=1) ls += __shfl_down(ls, off);
    __shared__ float wsum[4];
    if (lane == 0) wsum[w] = ls;
    __syncthreads();
    if (tid == 0) atomicAdd(loss + 0, wsum[0]+wsum[1]+wsum[2]+wsum[3]);
}

__global__ void finalize_kernel(float* __restrict__ loss){
    if (threadIdx.x == 0 && blockIdx.x == 0){
        loss[0] = loss[0] * (1.0f/6291456.0f);
        float c = loss[1] * (1.0f/33554432.0f);
        loss[1] = c;
        loss[2] = c;
    }
}

extern "C" void kernel_launch(void* const* d_in, const int* in_sizes, int n_in,
                              void* d_out, int out_size, void* d_ws, size_t ws_size,
                              hipStream_t stream)
{
    (void)in_sizes; (void)n_in; (void)out_size; (void)ws_size;
    const float* frames   = (const float*)d_in[0];
    const float* enc_w1   = (const float*)d_in[1];
    const float* enc_b1   = (const float*)d_in[2];
    const float* enc_w2   = (const float*)d_in[3];
    const float* enc_b2   = (const float*)d_in[4];
    const float* enc_w3   = (const float*)d_in[5];
    const float* enc_b3   = (const float*)d_in[6];
    const float* codebook = (const float*)d_in[7];
    const float* dec_w1   = (const float*)d_in[8];
    const float* dec_b1   = (const float*)d_in[9];
    const float* dec_w2   = (const float*)d_in[10];
    const float* dec_b2   = (const float*)d_in[11];
    const float* dec_w3   = (const float*)d_in[12];
    const float* dec_b3   = (const float*)d_in[13];

    // workspace: two [T,256] f32 regions (268 MB total, proven available)
    float* P = (float*)d_ws;                 // h1 -> z_e -> Y1(bf16)
    float* Q = P + (size_t)33554432;         // h2 -> {Y2(bf16) base, partials}
    float4* partials = (float4*)(Q + 18000000);  // 8.4 MB, disjoint from Y2
    ushort* Y1 = (ushort*)P;
    ushort* Y2 = (ushort*)Q;

    // outputs; recon region doubles as scratch for small constants
    float* recon = (float*)d_out;            // 6,291,456 f32 (written last)
    float* tokf  = recon + 6291456;          // 131,072
    float* loss  = tokf + 131072;            // 3
    float*  cn   = recon;                            // 512 f32
    ushort* cbb  = (ushort*)(recon + 512);           // 131072 us
    ushort* w1b  = (ushort*)(recon + 66048);         // 65536 us
    ushort* w2b  = (ushort*)(recon + 98816);         // 65536 us
    ushort* w2s0 = (ushort*)(recon + 131584);        // 65536 us each
    ushort* w2s1 = (ushort*)(recon + 164352);
    ushort* w2s2 = (ushort*)(recon + 197120);
    ushort* w3s0 = (ushort*)(recon + 229888);
    ushort* w3s1 = (ushort*)(recon + 262656);
    ushort* w3s2 = (ushort*)(recon + 295424);        // ends at 328192 < 6.29M

    hipMemsetAsync(loss, 0, 3*sizeof(float), stream);

    dim3 blk(256), grid2(T_ROWS/128, 2);
    // weight prep
    wsplit_kernel<<<dim3(64), blk, 0, stream>>>(enc_w2, enc_w3, dec_w1, dec_w2,
        w2s0, w2s1, w2s2, w3s0, w3s1, w3s2, w1b, w2b);
    cnorm_kernel<<<dim3(128), blk, 0, stream>>>(codebook, cn, cbb);
    // encoder: f32 layer1, then f32-faithful 6-term split-bf16 MFMA
    gemm_kernel<48, true, 1><<<grid2, blk, 0, stream>>>(nullptr, frames, enc_w1, enc_b1, P);
    split6_gemm<true ><<<grid2, blk, 0, stream>>>(P, w2s0, w2s1, w2s2, enc_b2, Q);
    split6_gemm<false><<<grid2, blk, 0, stream>>>(Q, w3s0, w3s1, w3s2, enc_b3, P);
    // vector quantization: bf16 approx + exact f32 rescore
    tokens_mfma<<<dim3(T_ROWS/128, 4), blk, 0, stream>>>(P, cbb, cn, partials);
    rescore_kernel<<<dim3(2048), blk, 0, stream>>>(P, codebook, cn, partials, tokf, loss);
    // decoder (bf16 MFMA)
    mfma_gemm<1><<<grid2, blk, 0, stream>>>(nullptr, cbb, tokf, w1b, dec_b1, Y1);
    mfma_gemm<0><<<grid2, blk, 0, stream>>>(Y1, nullptr, nullptr, w2b, dec_b2, Y2);
    dec3_mfma<<<dim3(T_ROWS/256), blk, 0, stream>>>(Y2, dec_w3, dec_b3, frames, recon, loss);
    finalize_kernel<<<dim3(1), dim3(64), 0, stream>>>(loss);
}